// Round 8
// baseline (315.246 us; speedup 1.0000x reference)
//
#include <hip/hip_runtime.h>
#include <hip/hip_bf16.h>

typedef __attribute__((ext_vector_type(4))) float f32x4;
typedef __attribute__((ext_vector_type(8))) short bf16x8;

#define SDIM 256
#define HID 1024
#define ADIM 64
#define MROWS 65536
#define CHUNK 16
#define NCHUNK 128
#define NCH 32768  // BATCH * HID

// ws layout: bbuf2 [0,128M) as [b][t][h];
// Sbuf [128M,144M); Cbuf [144M,160M); bwb [160M,160.5M); cwb [160.5M,160.625M)
#define WS_SBUF 134217728ull
#define WS_CBUF 150994944ull
#define WS_BWB  167772160ull
#define WS_CWB  168296448ull
#define WS_NEED 168427520ull

__device__ __forceinline__ unsigned short f2bf(float f) {
  unsigned int u = __float_as_uint(f);
  u += 0x7FFF + ((u >> 16) & 1);  // RNE
  return (unsigned short)(u >> 16);
}
__device__ __forceinline__ float bf2f(unsigned short h) {
  return __uint_as_float(((unsigned int)h) << 16);
}
__device__ __forceinline__ float fast_exp2(float x) {
  float r;
  asm volatile("v_exp_f32 %0, %1" : "=v"(r) : "v"(x));
  return r;
}
__device__ __forceinline__ float fast_rcp(float x) {
  float r;
  asm volatile("v_rcp_f32 %0, %1" : "=v"(r) : "v"(x));
  return r;
}
#define LOG2E 1.4426950408889634f

// -------- pre-convert fp32 -> bf16 (B_w, C_w only; tiny) --------
#define CVT_BN 262144  // B_w floats
#define CVT_CN 65536   // C_w floats
__global__ __launch_bounds__(256) void k_cvt(
    const float* __restrict__ bw, const float* __restrict__ cw,
    unsigned short* __restrict__ bwb, unsigned short* __restrict__ cwb) {
  long long f = ((long long)blockIdx.x * 256 + threadIdx.x) * 8;
  const float* src;
  unsigned short* dst;
  long long idx;
  if (f < CVT_BN) { src = bw; dst = bwb; idx = f; }
  else { src = cw; dst = cwb; idx = f - CVT_BN; }
  float4 a = *reinterpret_cast<const float4*>(src + idx);
  float4 b = *reinterpret_cast<const float4*>(src + idx + 4);
  ushort4 lo, hi;
  lo.x = f2bf(a.x); lo.y = f2bf(a.y); lo.z = f2bf(a.z); lo.w = f2bf(a.w);
  hi.x = f2bf(b.x); hi.y = f2bf(b.y); hi.z = f2bf(b.z); hi.w = f2bf(b.w);
  *reinterpret_cast<ushort4*>(dst + idx) = lo;
  *reinterpret_cast<ushort4*>(dst + idx + 4) = hi;
}

// ---- K1: b = states @ B_w^T + B_b -> bbuf2[b][t][h], BARRIER-FREE ----
// A frags straight from fp32 states (L2-hot slab), B frags from bf16 bwb.
// No staging LDS; 36KB LDS only for the per-wave store-transpose epilogue.
__global__ __launch_bounds__(256, 2) void k_gemm1p(
    const float* __restrict__ states, const unsigned short* __restrict__ bwb,
    const float* __restrict__ Bb, unsigned short* __restrict__ bout) {
  __shared__ char lds[36864];  // 4 waves x 9216B transpose scratch
  const int tid = threadIdx.x;
  const int wave = tid >> 6, lane = tid & 63;
  const int l15 = lane & 15, g = lane >> 4;
  const int bx = blockIdx.x;
  const int swzb = (bx & 7) * 512 + (bx >> 3);  // bijective XCD swizzle
  const int m0 = (swzb >> 3) * 128, n0 = (swzb & 7) * 128;
  const int wm = (wave >> 1) * 64, wn = (wave & 1) * 64;

  f32x4 acc[4][4];
#pragma unroll
  for (int i = 0; i < 4; i++)
#pragma unroll
    for (int j = 0; j < 4; j++) acc[i][j] = (f32x4){0.f, 0.f, 0.f, 0.f};

#pragma unroll
  for (int kt = 0; kt < 4; ++kt) {
    const int k0 = kt * 64;
    bf16x8 af[4][2], bfv[4][2];
#pragma unroll
    for (int f = 0; f < 4; ++f) {
      const float* ap = states + (size_t)(m0 + wm + f * 16 + l15) * SDIM + k0;
#pragma unroll
      for (int kk = 0; kk < 2; ++kk) {
        float4 lo = *reinterpret_cast<const float4*>(ap + kk * 32 + g * 8);
        float4 hi = *reinterpret_cast<const float4*>(ap + kk * 32 + g * 8 + 4);
        bf16x8 v;
        v[0] = (short)f2bf(lo.x); v[1] = (short)f2bf(lo.y);
        v[2] = (short)f2bf(lo.z); v[3] = (short)f2bf(lo.w);
        v[4] = (short)f2bf(hi.x); v[5] = (short)f2bf(hi.y);
        v[6] = (short)f2bf(hi.z); v[7] = (short)f2bf(hi.w);
        af[f][kk] = v;
      }
    }
#pragma unroll
    for (int f = 0; f < 4; ++f) {
      const unsigned short* bp = bwb + (size_t)(n0 + wn + f * 16 + l15) * SDIM + k0;
#pragma unroll
      for (int kk = 0; kk < 2; ++kk)
        bfv[f][kk] = *reinterpret_cast<const bf16x8*>(bp + kk * 32 + g * 8);
    }
#pragma unroll
    for (int kk = 0; kk < 2; ++kk)
#pragma unroll
      for (int i = 0; i < 4; ++i)
#pragma unroll
        for (int j = 0; j < 4; ++j)
          // swapped operands -> C^T fragments (lane holds 4 consecutive n)
          acc[i][j] = __builtin_amdgcn_mfma_f32_16x16x32_bf16(
              bfv[j][kk], af[i][kk], acc[i][j], 0, 0, 0);
  }

  // epilogue: bias + pack, per-wave LDS transpose, coalesced store to bbuf2
  char* wb = lds + wave * 9216;  // 64 rows x 144B
#pragma unroll
  for (int j = 0; j < 4; ++j) {
    float4 bb = *reinterpret_cast<const float4*>(Bb + n0 + wn + j * 16 + g * 4);
#pragma unroll
    for (int i = 0; i < 4; ++i) {
      ushort4 w;
      w.x = f2bf(acc[i][j][0] + bb.x);
      w.y = f2bf(acc[i][j][1] + bb.y);
      w.z = f2bf(acc[i][j][2] + bb.z);
      w.w = f2bf(acc[i][j][3] + bb.w);
      *reinterpret_cast<ushort4*>(wb + (i * 16 + l15) * 144 + j * 32 + g * 8) = w;
    }
  }
#pragma unroll
  for (int tt = 0; tt < 8; ++tt) {
    int ml = (lane >> 3) + tt * 8;
    int4 v = *reinterpret_cast<const int4*>(wb + ml * 144 + (lane & 7) * 16);
    int m = m0 + wm + ml;  // m = t*32 + batch
    size_t dst = ((size_t)(m & 31) * 2048 + (size_t)(m >> 5)) * HID +
                 n0 + wn + (lane & 7) * 8;
    *reinterpret_cast<int4*>(bout + dst) = v;
  }
}

// ------------- K2a: per-chunk partial scan sums (bbuf2 layout) -----------
__global__ __launch_bounds__(256) void k_scan_partial(
    const unsigned short* __restrict__ b2, const float* __restrict__ A_log,
    float* __restrict__ Sbuf) {
  int gid = blockIdx.x * 256 + threadIdx.x;
  int ch = (gid & 4095) * 8;
  int c = gid >> 12;
  int bb = ch >> 10;
  int hh = ch & 1023;
  float4 al0 = *reinterpret_cast<const float4*>(A_log + hh);
  float4 al1 = *reinterpret_cast<const float4*>(A_log + hh + 4);
  float a[8] = {__expf(al0.x), __expf(al0.y), __expf(al0.z), __expf(al0.w),
                __expf(al1.x), __expf(al1.y), __expf(al1.z), __expf(al1.w)};
  const unsigned short* p = b2 + (size_t)bb * 2097152 + (size_t)c * CHUNK * HID + hh;
  float s[8] = {0.f, 0.f, 0.f, 0.f, 0.f, 0.f, 0.f, 0.f};
#pragma unroll 4
  for (int j = 0; j < CHUNK; ++j) {
    int4 v = *reinterpret_cast<const int4*>(p + (size_t)j * HID);
    unsigned int u[4] = {(unsigned)v.x, (unsigned)v.y, (unsigned)v.z, (unsigned)v.w};
#pragma unroll
    for (int e = 0; e < 4; ++e) {
      s[2 * e]     = fmaf(a[2 * e],     s[2 * e],     __uint_as_float(u[e] << 16));
      s[2 * e + 1] = fmaf(a[2 * e + 1], s[2 * e + 1], __uint_as_float(u[e] & 0xFFFF0000u));
    }
  }
  float4 o0 = {s[0], s[1], s[2], s[3]}, o1 = {s[4], s[5], s[6], s[7]};
  *reinterpret_cast<float4*>(Sbuf + (size_t)c * NCH + ch) = o0;
  *reinterpret_cast<float4*>(Sbuf + (size_t)c * NCH + ch + 4) = o1;
}

// ------------- K2b: carry scan over chunks ----------------
__global__ __launch_bounds__(256) void k_scan_carry(
    const float* __restrict__ Sbuf, const float* __restrict__ A_log,
    float* __restrict__ Cbuf) {
  int ch = blockIdx.x * 256 + threadIdx.x;
  float aL = __expf(A_log[ch & (HID - 1)] * (float)CHUNK);
  float h = 0.f;
  for (int c = 0; c < NCHUNK; ++c) {
    Cbuf[(size_t)c * NCH + ch] = h;
    h = fmaf(aL, h, Sbuf[(size_t)c * NCH + ch]);
  }
}

// ---- K3 (fused): 2-phase/8-slice scan+tanh + mus GEMM + log-prob ----
// Block = one batch x 64 t. Thread = (slice, tq, h8): 8 h-chains x 16 t,
// int4 loads, ds_write_b128, 4 barriers total. B frags direct from L2.
__global__ __launch_bounds__(256, 2) void k_gemm2f(
    const unsigned short* __restrict__ b2, const float* __restrict__ actions,
    const unsigned short* __restrict__ cwb, const float* __restrict__ Cb,
    const float* __restrict__ log_std, const float* __restrict__ A_log,
    const float* __restrict__ Cbuf, float* __restrict__ out) {
  __shared__ char ldsA[65536];  // 8 slices x [64 t][64 h] bf16, XOR-swizzled
  const int tid = threadIdx.x;
  const int wave = tid >> 6, lane = tid & 63;
  const int l15 = lane & 15, g = lane >> 4;
  const int bq = blockIdx.x;
  const int bb = bq >> 5;          // batch
  const int t0 = (bq & 31) * 64;   // t-window
  const int c0 = (bq & 31) * 4;    // chunk base (CHUNK=16)
  const int wm = wave * 16;
  const int s  = tid >> 5;         // slice 0..7
  const int tq = (tid >> 3) & 3;   // t-quarter
  const int h8 = tid & 7;          // 8-h group

  const unsigned short* srcT =
      b2 + (size_t)bb * 2097152 + (size_t)(t0 + tq * 16) * HID;

  f32x4 acc[4];
#pragma unroll
  for (int j = 0; j < 4; ++j) acc[j] = (f32x4){0.f, 0.f, 0.f, 0.f};

  int4 va[16];
  float al[8], cbv[8];
  // prologue: phase-0 prefetch (scan columns + carries + A_log)
  {
    const int hb = s * 64 + h8 * 8;
#pragma unroll
    for (int j = 0; j < 16; ++j)
      va[j] = *reinterpret_cast<const int4*>(srcT + (size_t)j * HID + hb);
    float4 a0 = *reinterpret_cast<const float4*>(A_log + hb);
    float4 a1 = *reinterpret_cast<const float4*>(A_log + hb + 4);
    const float* cp = Cbuf + (size_t)(c0 + tq) * NCH + bb * 1024 + hb;
    float4 q0 = *reinterpret_cast<const float4*>(cp);
    float4 q1 = *reinterpret_cast<const float4*>(cp + 4);
    al[0]=a0.x; al[1]=a0.y; al[2]=a0.z; al[3]=a0.w;
    al[4]=a1.x; al[5]=a1.y; al[6]=a1.z; al[7]=a1.w;
    cbv[0]=q0.x; cbv[1]=q0.y; cbv[2]=q0.z; cbv[3]=q0.w;
    cbv[4]=q1.x; cbv[5]=q1.y; cbv[6]=q1.z; cbv[7]=q1.w;
  }

#pragma unroll
  for (int p = 0; p < 2; ++p) {
    // ---- scan: 8 chains x 16 t, tanh, packed swizzled LDS write ----
    {
      float a[8], hst[8];
#pragma unroll
      for (int e = 0; e < 8; ++e) {
        a[e] = fast_exp2(al[e] * LOG2E);
        hst[e] = cbv[e];
      }
      char* wp = ldsA + s * 8192;
#pragma unroll
      for (int j = 0; j < 16; ++j) {
        unsigned int u[4] = {(unsigned)va[j].x, (unsigned)va[j].y,
                             (unsigned)va[j].z, (unsigned)va[j].w};
        unsigned short ob[8];
#pragma unroll
        for (int e = 0; e < 8; ++e) {
          unsigned int bits = (e & 1) ? (u[e >> 1] & 0xFFFF0000u) : (u[e >> 1] << 16);
          hst[e] = fmaf(a[e], hst[e], __uint_as_float(bits));
          float ex = fast_exp2(hst[e] * (2.0f * LOG2E));
          ob[e] = f2bf(fmaf(-2.0f, fast_rcp(ex + 1.0f), 1.0f));
        }
        int row = tq * 16 + j;
        int4 o;
        o.x = (int)((unsigned)ob[0] | ((unsigned)ob[1] << 16));
        o.y = (int)((unsigned)ob[2] | ((unsigned)ob[3] << 16));
        o.z = (int)((unsigned)ob[4] | ((unsigned)ob[5] << 16));
        o.w = (int)((unsigned)ob[6] | ((unsigned)ob[7] << 16));
        *reinterpret_cast<int4*>(wp + row * 128 + ((h8 ^ (row & 7)) << 4)) = o;
      }
    }
    // ---- prefetch phase-1 while MFMA phase runs (T14) ----
    if (p == 0) {
      const int hb = 512 + s * 64 + h8 * 8;
#pragma unroll
      for (int j = 0; j < 16; ++j)
        va[j] = *reinterpret_cast<const int4*>(srcT + (size_t)j * HID + hb);
      float4 a0 = *reinterpret_cast<const float4*>(A_log + hb);
      float4 a1 = *reinterpret_cast<const float4*>(A_log + hb + 4);
      const float* cp = Cbuf + (size_t)(c0 + tq) * NCH + bb * 1024 + hb;
      float4 q0 = *reinterpret_cast<const float4*>(cp);
      float4 q1 = *reinterpret_cast<const float4*>(cp + 4);
      al[0]=a0.x; al[1]=a0.y; al[2]=a0.z; al[3]=a0.w;
      al[4]=a1.x; al[5]=a1.y; al[6]=a1.z; al[7]=a1.w;
      cbv[0]=q0.x; cbv[1]=q0.y; cbv[2]=q0.z; cbv[3]=q0.w;
      cbv[4]=q1.x; cbv[5]=q1.y; cbv[6]=q1.z; cbv[7]=q1.w;
    }
    asm volatile("s_waitcnt lgkmcnt(0)" ::: "memory");
    __builtin_amdgcn_s_barrier();
    __builtin_amdgcn_sched_barrier(0);
    // ---- MFMA: 8 rounds; A from LDS slice, B direct from L2-hot cwb ----
#pragma unroll
    for (int s2 = 0; s2 < 8; ++s2) {
      const int ktg = p * 8 + s2;
      bf16x8 af[2], bfv[4][2];
#pragma unroll
      for (int kk = 0; kk < 2; ++kk) {
        int slotsw = ((kk * 4 + g) ^ (l15 & 7)) * 16;
        af[kk] = *reinterpret_cast<const bf16x8*>(
            ldsA + s2 * 8192 + (wm + l15) * 128 + slotsw);
#pragma unroll
        for (int f = 0; f < 4; ++f)
          bfv[f][kk] = *reinterpret_cast<const bf16x8*>(
              (const char*)cwb + (size_t)(f * 16 + l15) * 2048 + ktg * 128 +
              (kk * 4 + g) * 16);
      }
#pragma unroll
      for (int kk = 0; kk < 2; ++kk)
#pragma unroll
        for (int j = 0; j < 4; ++j)
          acc[j] = __builtin_amdgcn_mfma_f32_16x16x32_bf16(
              af[kk], bfv[j][kk], acc[j], 0, 0, 0);
    }
    if (p == 0) {
      __builtin_amdgcn_s_barrier();  // readers done before phase-1 writes
      __builtin_amdgcn_sched_barrier(0);
    }
  }
  // fused epilogue: log_pi row-sum over 64 action dims
  float istd[4], cb[4];
#pragma unroll
  for (int j = 0; j < 4; ++j) {
    int n = j * 16 + l15;
    istd[j] = __expf(-log_std[n]);
    cb[j] = Cb[n];
  }
  float sls = 0.f;
  for (int n = 0; n < ADIM; ++n) sls += log_std[n];
  const float cterm = -32.0f * 1.8378770664093453f - sls;
  const int rb = wm + g * 4;
#pragma unroll
  for (int r = 0; r < 4; ++r) {
    int rl = rb + r;                 // local t-row (0..63)
    int mo = (t0 + rl) * 32 + bb;    // original row index [L,B]
    float ss = 0.f;
#pragma unroll
    for (int j = 0; j < 4; ++j) {
      int n = j * 16 + l15;
      float mu = acc[j][r] + cb[j];
      float d = (actions[(size_t)mo * ADIM + n] - mu) * istd[j];
      ss = fmaf(d, d, ss);
    }
    ss += __shfl_xor(ss, 1);
    ss += __shfl_xor(ss, 2);
    ss += __shfl_xor(ss, 4);
    ss += __shfl_xor(ss, 8);
    if (l15 == 0) out[mo] = cterm - 0.5f * ss;
  }
}

// ===================== fallback (round-1 proven, OLD [m][h] layout) ========
__device__ __forceinline__ int swz_fb(int row, int byteInRow) {
  int slot = (byteInRow >> 4) & 3;
  slot = (slot + (row >> 1)) & 3;
  return row * 64 + slot * 16 + (byteInRow & 15);
}

__global__ __launch_bounds__(256) void k_gemm1_fb(
    const float* __restrict__ states, const float* __restrict__ Bw,
    const float* __restrict__ Bb, unsigned short* __restrict__ bout) {
  __shared__ char ldsmem[2 * 128 * 64];
  char* ldsA = ldsmem;
  char* ldsB = ldsmem + 128 * 64;
  const int tid = threadIdx.x;
  const int bx = blockIdx.x;
  const int mt = bx >> 3, nt = bx & 7;
  const int m0 = mt * 128, n0 = nt * 128;
  const int wave = tid >> 6, lane = tid & 63;
  const int wm = (wave >> 1) * 64, wn = (wave & 1) * 64;
  const int sr = tid >> 3;
  const int sc = tid & 7;
  f32x4 acc[4][4];
  for (int i = 0; i < 4; i++)
    for (int j = 0; j < 4; j++) acc[i][j] = (f32x4){0.f, 0.f, 0.f, 0.f};
  const int l15 = lane & 15;
  const int slot16 = (lane >> 4) * 16;
  int offA[4], offB[4], wrOff[4];
  for (int f = 0; f < 4; ++f) {
    offA[f] = swz_fb(wm + f * 16 + l15, slot16);
    offB[f] = swz_fb(wn + f * 16 + l15, slot16);
  }
  for (int p = 0; p < 4; ++p) wrOff[p] = swz_fb(sr + p * 32, sc * 8);
  for (int kt = 0; kt < 8; ++kt) {
    const int k0 = kt * 32;
    for (int p = 0; p < 4; ++p) {
      int r = sr + p * 32;
      float4 va = *reinterpret_cast<const float4*>(states + (size_t)(m0 + r) * SDIM + k0 + sc * 4);
      float4 vb = *reinterpret_cast<const float4*>(Bw + (size_t)(n0 + r) * SDIM + k0 + sc * 4);
      ushort4 wa, wb2;
      wa.x = f2bf(va.x); wa.y = f2bf(va.y); wa.z = f2bf(va.z); wa.w = f2bf(va.w);
      wb2.x = f2bf(vb.x); wb2.y = f2bf(vb.y); wb2.z = f2bf(vb.z); wb2.w = f2bf(vb.w);
      *reinterpret_cast<ushort4*>(ldsA + wrOff[p]) = wa;
      *reinterpret_cast<ushort4*>(ldsB + wrOff[p]) = wb2;
    }
    __syncthreads();
    bf16x8 af[4], bfv[4];
    for (int f = 0; f < 4; ++f) {
      af[f] = *reinterpret_cast<const bf16x8*>(ldsA + offA[f]);
      bfv[f] = *reinterpret_cast<const bf16x8*>(ldsB + offB[f]);
    }
    for (int i = 0; i < 4; ++i)
      for (int j = 0; j < 4; ++j)
        acc[i][j] = __builtin_amdgcn_mfma_f32_16x16x32_bf16(af[i], bfv[j], acc[i][j], 0, 0, 0);
    __syncthreads();
  }
  const int colg = n0 + wn + l15;
  const int rowg = m0 + wm + (lane >> 4) * 4;
  for (int j = 0; j < 4; ++j) {
    float bbv = Bb[colg + j * 16];
    for (int i = 0; i < 4; ++i)
      for (int r = 0; r < 4; ++r) {
        int row = rowg + i * 16 + r;
        bout[(size_t)row * HID + colg + j * 16] = f2bf(acc[i][j][r] + bbv);
      }
  }
}

__global__ __launch_bounds__(256) void k_scan_partial_fb(
    const unsigned short* __restrict__ b, const float* __restrict__ A_log,
    float* __restrict__ Sbuf) {
  int gid = blockIdx.x * 256 + threadIdx.x;
  int ch = (gid & 4095) * 8;
  int c = gid >> 12;
  float4 al0 = *reinterpret_cast<const float4*>(A_log + (ch & (HID - 1)));
  float4 al1 = *reinterpret_cast<const float4*>(A_log + (ch & (HID - 1)) + 4);
  float a[8] = {__expf(al0.x), __expf(al0.y), __expf(al0.z), __expf(al0.w),
                __expf(al1.x), __expf(al1.y), __expf(al1.z), __expf(al1.w)};
  const unsigned short* p = b + (size_t)c * CHUNK * NCH + ch;
  float s[8] = {0.f, 0.f, 0.f, 0.f, 0.f, 0.f, 0.f, 0.f};
#pragma unroll 4
  for (int j = 0; j < CHUNK; ++j) {
    int4 v = *reinterpret_cast<const int4*>(p + (size_t)j * NCH);
    unsigned int u[4] = {(unsigned)v.x, (unsigned)v.y, (unsigned)v.z, (unsigned)v.w};
#pragma unroll
    for (int e = 0; e < 4; ++e) {
      s[2 * e]     = fmaf(a[2 * e],     s[2 * e],     __uint_as_float(u[e] << 16));
      s[2 * e + 1] = fmaf(a[2 * e + 1], s[2 * e + 1], __uint_as_float(u[e] & 0xFFFF0000u));
    }
  }
  float4 o0 = {s[0], s[1], s[2], s[3]}, o1 = {s[4], s[5], s[6], s[7]};
  *reinterpret_cast<float4*>(Sbuf + (size_t)c * NCH + ch) = o0;
  *reinterpret_cast<float4*>(Sbuf + (size_t)c * NCH + ch + 4) = o1;
}

__global__ __launch_bounds__(256) void k_scan_final_fb(
    unsigned short* __restrict__ b, const float* __restrict__ A_log,
    const float* __restrict__ Cbuf) {
  int gid = blockIdx.x * 256 + threadIdx.x;
  int ch = (gid & 4095) * 8;
  int c = gid >> 12;
  float4 al0 = *reinterpret_cast<const float4*>(A_log + (ch & (HID - 1)));
  float4 al1 = *reinterpret_cast<const float4*>(A_log + (ch & (HID - 1)) + 4);
  float a[8] = {__expf(al0.x), __expf(al0.y), __expf(al0.z), __expf(al0.w),
                __expf(al1.x), __expf(al1.y), __expf(al1.z), __expf(al1.w)};
  unsigned short* p = b + (size_t)c * CHUNK * NCH + ch;
  float4 h0 = *reinterpret_cast<const float4*>(Cbuf + (size_t)c * NCH + ch);
  float4 h1 = *reinterpret_cast<const float4*>(Cbuf + (size_t)c * NCH + ch + 4);
  float h[8] = {h0.x, h0.y, h0.z, h0.w, h1.x, h1.y, h1.z, h1.w};
#pragma unroll 2
  for (int j = 0; j < CHUNK; ++j) {
    int4 v = *reinterpret_cast<const int4*>(p + (size_t)j * NCH);
    unsigned int u[4] = {(unsigned)v.x, (unsigned)v.y, (unsigned)v.z, (unsigned)v.w};
    unsigned short ob[8];
#pragma unroll
    for (int e = 0; e < 8; ++e) {
      unsigned int bits = (e & 1) ? (u[e >> 1] & 0xFFFF0000u) : (u[e >> 1] << 16);
      h[e] = fmaf(a[e], h[e], __uint_as_float(bits));
      float ex = __expf(2.0f * h[e]);
      ob[e] = f2bf(1.0f - 2.0f / (ex + 1.0f));
    }
    int4 o;
    o.x = (int)((unsigned)ob[0] | ((unsigned)ob[1] << 16));
    o.y = (int)((unsigned)ob[2] | ((unsigned)ob[3] << 16));
    o.z = (int)((unsigned)ob[4] | ((unsigned)ob[5] << 16));
    o.w = (int)((unsigned)ob[6] | ((unsigned)ob[7] << 16));
    *reinterpret_cast<int4*>(p + (size_t)j * NCH) = o;
  }
}

__global__ __launch_bounds__(256) void k_gemm2_fb(
    const unsigned short* __restrict__ hbuf, const float* __restrict__ actions,
    const float* __restrict__ Cw, const float* __restrict__ Cb,
    const float* __restrict__ log_std, float* __restrict__ out) {
  __shared__ char ldsmem[128 * 64 + 64 * 64];
  char* ldsA = ldsmem;
  char* ldsB = ldsmem + 128 * 64;
  const int tid = threadIdx.x;
  const int m0 = blockIdx.x * 128;
  const int wave = tid >> 6, lane = tid & 63;
  const int wrow = wave * 32;
  const int l15 = lane & 15;
  const int slot16 = (lane >> 4) * 16;
  f32x4 acc[2][4];
  for (int i = 0; i < 2; i++)
    for (int j = 0; j < 4; j++) acc[i][j] = (f32x4){0.f, 0.f, 0.f, 0.f};
  const int cA = tid & 3, rA = tid >> 2;
  const int cB = tid & 7, rB = tid >> 3;
  int offA[2], offB[4], wrA[2], wrB[2];
  for (int f = 0; f < 2; ++f) offA[f] = swz_fb(wrow + f * 16 + l15, slot16);
  for (int f = 0; f < 4; ++f) offB[f] = swz_fb(f * 16 + l15, slot16);
  for (int p = 0; p < 2; ++p) wrA[p] = swz_fb(rA + p * 64, cA * 16);
  for (int p = 0; p < 2; ++p) wrB[p] = swz_fb(rB + p * 32, cB * 8);
  for (int kt = 0; kt < 32; ++kt) {
    int k0 = kt * 32;
    for (int p = 0; p < 2; ++p) {
      int r = rA + p * 64;
      int4 v = *reinterpret_cast<const int4*>(hbuf + (size_t)(m0 + r) * HID + k0 + cA * 8);
      *reinterpret_cast<int4*>(ldsA + wrA[p]) = v;
    }
    for (int p = 0; p < 2; ++p) {
      int r = rB + p * 32;
      float4 v = *reinterpret_cast<const float4*>(Cw + (size_t)r * HID + k0 + cB * 4);
      ushort4 w;
      w.x = f2bf(v.x); w.y = f2bf(v.y); w.z = f2bf(v.z); w.w = f2bf(v.w);
      *reinterpret_cast<ushort4*>(ldsB + wrB[p]) = w;
    }
    __syncthreads();
    bf16x8 af[2], bfv[4];
    for (int f = 0; f < 2; ++f) af[f] = *reinterpret_cast<const bf16x8*>(ldsA + offA[f]);
    for (int f = 0; f < 4; ++f) bfv[f] = *reinterpret_cast<const bf16x8*>(ldsB + offB[f]);
    for (int i = 0; i < 2; ++i)
      for (int j = 0; j < 4; ++j)
        acc[i][j] = __builtin_amdgcn_mfma_f32_16x16x32_bf16(af[i], bfv[j], acc[i][j], 0, 0, 0);
    __syncthreads();
  }
  float istd[4], cb[4];
  for (int j = 0; j < 4; ++j) {
    int n = j * 16 + l15;
    istd[j] = __expf(-log_std[n]);
    cb[j] = Cb[n];
  }
  float sls = 0.f;
  for (int n = 0; n < 64; ++n) sls += log_std[n];
  const float cterm = -32.0f * 1.8378770664093453f - sls;
  const int rbase = m0 + wrow + (lane >> 4) * 4;
  for (int i = 0; i < 2; ++i)
    for (int r = 0; r < 4; ++r) {
      int row = rbase + i * 16 + r;
      float ss = 0.f;
      for (int j = 0; j < 4; ++j) {
        int n = j * 16 + l15;
        float mu = acc[i][j][r] + cb[j];
        float d = (actions[(size_t)row * ADIM + n] - mu) * istd[j];
        ss = fmaf(d, d, ss);
      }
      ss += __shfl_xor(ss, 1);
      ss += __shfl_xor(ss, 2);
      ss += __shfl_xor(ss, 4);
      ss += __shfl_xor(ss, 8);
      if (l15 == 0) out[row] = cterm - 0.5f * ss;
    }
}

extern "C" void kernel_launch(void* const* d_in, const int* in_sizes, int n_in,
                              void* d_out, int out_size, void* d_ws, size_t ws_size,
                              hipStream_t stream) {
  const float* states  = (const float*)d_in[0];
  const float* actions = (const float*)d_in[1];
  const float* A_log   = (const float*)d_in[2];
  const float* B_w     = (const float*)d_in[3];
  const float* B_b     = (const float*)d_in[4];
  const float* C_w     = (const float*)d_in[5];
  const float* C_b     = (const float*)d_in[6];
  const float* log_std = (const float*)d_in[7];
  float* out = (float*)d_out;
  char* ws = (char*)d_ws;

  unsigned short* bbuf = (unsigned short*)ws;
  float* Sbuf = (float*)(ws + WS_SBUF);
  float* Cbuf = (float*)(ws + WS_CBUF);
  const int scan_grid = NCHUNK * 4096 / 256;  // 2048 blocks

  if (ws_size >= WS_NEED) {
    unsigned short* bwb = (unsigned short*)(ws + WS_BWB);
    unsigned short* cwb = (unsigned short*)(ws + WS_CWB);
    k_cvt<<<160, 256, 0, stream>>>(B_w, C_w, bwb, cwb);
    k_gemm1p<<<4096, 256, 0, stream>>>(states, bwb, B_b, bbuf);
    k_scan_partial<<<scan_grid, 256, 0, stream>>>(bbuf, A_log, Sbuf);
    k_scan_carry<<<128, 256, 0, stream>>>(Sbuf, A_log, Cbuf);
    k_gemm2f<<<1024, 256, 0, stream>>>(bbuf, actions, cwb, C_b, log_std, A_log,
                                       Cbuf, out);
  } else {
    k_gemm1_fb<<<4096, 256, 0, stream>>>(states, B_w, B_b, bbuf);
    k_scan_partial_fb<<<scan_grid, 256, 0, stream>>>(bbuf, A_log, Sbuf);
    k_scan_carry<<<128, 256, 0, stream>>>(Sbuf, A_log, Cbuf);
    k_scan_final_fb<<<scan_grid, 256, 0, stream>>>(bbuf, A_log, Cbuf);
    k_gemm2_fb<<<512, 256, 0, stream>>>(bbuf, actions, C_w, C_b, log_std, out);
  }
}

// Round 9
// 175.197 us; speedup vs baseline: 1.7994x; 1.7994x over previous
//
#include <hip/hip_runtime.h>
#include <hip/hip_bf16.h>

typedef __attribute__((ext_vector_type(4))) float f32x4;
typedef __attribute__((ext_vector_type(8))) short bf16x8;

#define SDIM 256
#define HID 1024
#define ADIM 64
#define CHUNK 16
#define NCHUNK 128
#define NCH 32768  // BATCH * HID

// ws layout (both tiers): bbuf2 [0,128M) as [b][t][h]; stb [128M,160M)
// Tier-1 (fused): SCbuf [160M,176M); bwb/cwb after -> WS_NEED_F
// Tier-2 (r7):    Sbuf/Cbuf alias stb after gemm1p; bwb/cwb at 160M
#define WS_STB   134217728ull
#define WS_SCB   167772160ull
#define WS_BWB_F 184549376ull
#define WS_CWB_F 185073664ull
#define WS_NEED_F 185204736ull
// tier-2 (round-7 proven)
#define WS_SBUF2 134217728ull
#define WS_CBUF2 150994944ull
#define WS_BWB2  167772160ull
#define WS_CWB2  168296448ull
#define WS_NEED2 168427520ull

__device__ __forceinline__ unsigned short f2bf(float f) {
  unsigned int u = __float_as_uint(f);
  u += 0x7FFF + ((u >> 16) & 1);  // RNE
  return (unsigned short)(u >> 16);
}
__device__ __forceinline__ float bf2f(unsigned short h) {
  return __uint_as_float(((unsigned int)h) << 16);
}
__device__ __forceinline__ float fast_exp2(float x) {
  float r;
  asm volatile("v_exp_f32 %0, %1" : "=v"(r) : "v"(x));
  return r;
}
__device__ __forceinline__ float fast_rcp(float x) {
  float r;
  asm volatile("v_rcp_f32 %0, %1" : "=v"(r) : "v"(x));
  return r;
}
#define LOG2E 1.4426950408889634f

#define GLDS16(gp, lp)                                                        \
  __builtin_amdgcn_global_load_lds(                                           \
      (const __attribute__((address_space(1))) unsigned int*)(gp),            \
      (__attribute__((address_space(3))) unsigned int*)(lp), 16, 0, 0)

// ---------------- pre-convert fp32 -> bf16 (states, B_w, C_w) --------------
// perm=1: write states rows in m2-order (batch-major: m2=(m&31)*2048+(m>>5))
#define CVT_SN 16777216
#define CVT_BN 262144
#define CVT_CN 65536
__global__ __launch_bounds__(256) void k_cvt(
    const float* __restrict__ s, const float* __restrict__ bw,
    const float* __restrict__ cw, unsigned short* __restrict__ sb,
    unsigned short* __restrict__ bwb, unsigned short* __restrict__ cwb,
    int perm) {
  long long f = ((long long)blockIdx.x * 256 + threadIdx.x) * 8;
  const float* src;
  unsigned short* dst;
  long long idx, didx;
  if (f < CVT_SN) {
    src = s; dst = sb; idx = f;
    if (perm) {
      long long m = f >> 8, col = f & 255;
      didx = ((m & 31) * 2048 + (m >> 5)) * 256 + col;
    } else didx = f;
  } else if (f < CVT_SN + CVT_BN) {
    src = bw; dst = bwb; idx = f - CVT_SN; didx = idx;
  } else {
    src = cw; dst = cwb; idx = f - CVT_SN - CVT_BN; didx = idx;
  }
  float4 a = *reinterpret_cast<const float4*>(src + idx);
  float4 b = *reinterpret_cast<const float4*>(src + idx + 4);
  ushort4 lo, hi;
  lo.x = f2bf(a.x); lo.y = f2bf(a.y); lo.z = f2bf(a.z); lo.w = f2bf(a.w);
  hi.x = f2bf(b.x); hi.y = f2bf(b.y); hi.z = f2bf(b.z); hi.w = f2bf(b.w);
  *reinterpret_cast<ushort4*>(dst + didx) = lo;
  *reinterpret_cast<ushort4*>(dst + didx + 4) = hi;
}

// -------------------- shared GEMM1 compute (r4/r7 proven) ------------------
__device__ __forceinline__ void g1_compute(
    const char* bA, const char* bB, f32x4 (&acc)[4][4],
    int wm, int wn, int l15, int g) {
  bf16x8 af[4][2], bfv[4][2];
#pragma unroll
  for (int kk = 0; kk < 2; ++kk) {
    int slotsw = ((kk * 4 + g) ^ (l15 & 7)) * 16;
#pragma unroll
    for (int f = 0; f < 4; ++f) {
      af[f][kk] = *reinterpret_cast<const bf16x8*>(bA + (wm + f * 16 + l15) * 128 + slotsw);
      bfv[f][kk] = *reinterpret_cast<const bf16x8*>(bB + (wn + f * 16 + l15) * 128 + slotsw);
    }
  }
#pragma unroll
  for (int kk = 0; kk < 2; ++kk)
#pragma unroll
    for (int i = 0; i < 4; ++i)
#pragma unroll
      for (int j = 0; j < 4; ++j)
        acc[i][j] = __builtin_amdgcn_mfma_f32_16x16x32_bf16(
            bfv[j][kk], af[i][kk], acc[i][j], 0, 0, 0);
}

#define STAGE1(tile, buf)                                                     \
  {                                                                           \
    const int k0b_ = (tile) * 128;                                            \
    char* dA_ = lds + (buf) * 32768;                                          \
    char* dB_ = lds + 16384 + (buf) * 32768;                                  \
    _Pragma("unroll")                                                         \
    for (int p = 0; p < 4; ++p) {                                             \
      int chunk = wave * 4 + p;                                               \
      GLDS16((const char*)sb + ((size_t)(m0 + chunk * 8 + srow) * SDIM) * 2 + \
                 k0b_ + swslot * 16,                                          \
             dA_ + chunk * 1024);                                             \
      GLDS16((const char*)bwb + ((size_t)(n0 + chunk * 8 + srow) * SDIM) * 2 +\
                 k0b_ + swslot * 16,                                          \
             dB_ + chunk * 1024);                                             \
    }                                                                         \
  }

#define G1_PIPELINE()                                                         \
  STAGE1(0, 0);                                                               \
  for (int t = 0; t < 3; ++t) {                                               \
    const int cur = t & 1;                                                    \
    STAGE1(t + 1, cur ^ 1);                                                   \
    asm volatile("s_waitcnt vmcnt(8)" ::: "memory");                          \
    __builtin_amdgcn_s_barrier();                                             \
    __builtin_amdgcn_sched_barrier(0);                                        \
    g1_compute(lds + cur * 32768, lds + 16384 + cur * 32768, acc, wm, wn,     \
               l15, g);                                                       \
    __builtin_amdgcn_s_barrier();                                             \
    __builtin_amdgcn_sched_barrier(0);                                        \
  }                                                                           \
  asm volatile("s_waitcnt vmcnt(0)" ::: "memory");                            \
  __builtin_amdgcn_s_barrier();                                               \
  __builtin_amdgcn_sched_barrier(0);                                          \
  g1_compute(lds + 32768, lds + 16384 + 32768, acc, wm, wn, l15, g);          \
  __builtin_amdgcn_s_barrier();                                               \
  __builtin_amdgcn_sched_barrier(0);

// ---- K1 tier-1: b = states@B_w^T+B_b -> bbuf2 (m2-order tiles) ----
// Same staging/MFMA as r7; epilogue additionally emits the per-16t chunk
// partial sums (replaces k_scan_partial). Fragment layout (r7-verified):
// acc[i][j][r]: m = wm+i*16+l15, h = wn+j*16+g*4+r.
__global__ __launch_bounds__(256) void k_gemm1p_f(
    const unsigned short* __restrict__ sb, const unsigned short* __restrict__ bwb,
    const float* __restrict__ Bb, const float* __restrict__ A_log,
    unsigned short* __restrict__ bout, float* __restrict__ Sb) {
  __shared__ char lds[65536];
  const int tid = threadIdx.x;
  const int wave = tid >> 6, lane = tid & 63;
  const int l15 = lane & 15, g = lane >> 4;
  const int bx = blockIdx.x;
  const int swzb = (bx & 7) * 512 + (bx >> 3);  // bijective XCD swizzle
  const int mt = swzb >> 3, nt = swzb & 7;
  const int m0 = mt * 128, n0 = nt * 128;  // m0 is m2-row base (batch-major)
  const int bb2 = mt >> 4;                 // batch of this tile
  const int c0t = (mt & 15) * 8;           // global t-chunk base
  const int wm = (wave >> 1) * 64, wn = (wave & 1) * 64;
  const int srow = lane >> 3;
  const int swslot = (lane & 7) ^ srow;

  f32x4 acc[4][4];
#pragma unroll
  for (int i = 0; i < 4; i++)
#pragma unroll
    for (int j = 0; j < 4; j++) acc[i][j] = (f32x4){0.f, 0.f, 0.f, 0.f};

  G1_PIPELINE();

  // ---- fused chunk-partials: S[c][h] = sum_p a_h^(15-p) * (b+bias) ----
  {
    const float wexp = (float)(15 - l15) * LOG2E;
#pragma unroll
    for (int j = 0; j < 4; ++j) {
      float4 al4 = *reinterpret_cast<const float4*>(A_log + n0 + wn + j * 16 + g * 4);
      float4 bb4 = *reinterpret_cast<const float4*>(Bb + n0 + wn + j * 16 + g * 4);
      float w0 = fast_exp2(al4.x * wexp), w1 = fast_exp2(al4.y * wexp);
      float w2 = fast_exp2(al4.z * wexp), w3 = fast_exp2(al4.w * wexp);
#pragma unroll
      for (int i = 0; i < 4; ++i) {
        float u0 = (acc[i][j][0] + bb4.x) * w0;
        float u1 = (acc[i][j][1] + bb4.y) * w1;
        float u2 = (acc[i][j][2] + bb4.z) * w2;
        float u3 = (acc[i][j][3] + bb4.w) * w3;
#pragma unroll
        for (int mk = 1; mk <= 8; mk <<= 1) {
          u0 += __shfl_xor(u0, mk);
          u1 += __shfl_xor(u1, mk);
          u2 += __shfl_xor(u2, mk);
          u3 += __shfl_xor(u3, mk);
        }
        if (l15 == 0) {
          int c = c0t + (wm >> 4) + i;
          float4 o = {u0, u1, u2, u3};
          *reinterpret_cast<float4*>(
              Sb + (size_t)c * NCH + bb2 * 1024 + n0 + wn + j * 16 + g * 4) = o;
        }
      }
    }
  }

  // epilogue: bias + pack, per-wave LDS transpose, m2-linear coalesced store
  char* wb = lds + wave * 9216;
#pragma unroll
  for (int j = 0; j < 4; ++j) {
    float4 bb = *reinterpret_cast<const float4*>(Bb + n0 + wn + j * 16 + g * 4);
#pragma unroll
    for (int i = 0; i < 4; ++i) {
      ushort4 w;
      w.x = f2bf(acc[i][j][0] + bb.x);
      w.y = f2bf(acc[i][j][1] + bb.y);
      w.z = f2bf(acc[i][j][2] + bb.z);
      w.w = f2bf(acc[i][j][3] + bb.w);
      *reinterpret_cast<ushort4*>(wb + (i * 16 + l15) * 144 + j * 32 + g * 8) = w;
    }
  }
#pragma unroll
  for (int tt = 0; tt < 8; ++tt) {
    int ml = (lane >> 3) + tt * 8;
    int4 v = *reinterpret_cast<const int4*>(wb + ml * 144 + (lane & 7) * 16);
    *reinterpret_cast<int4*>(bout + (size_t)(m0 + wm + ml) * HID + n0 + wn +
                             (lane & 7) * 8) = v;
  }
}

// ---- K1 tier-2: r7 verbatim (m-order tiles, permuted store) ----
__global__ __launch_bounds__(256) void k_gemm1p_7(
    const unsigned short* __restrict__ sb, const unsigned short* __restrict__ bwb,
    const float* __restrict__ Bb, unsigned short* __restrict__ bout) {
  __shared__ char lds[65536];
  const int tid = threadIdx.x;
  const int wave = tid >> 6, lane = tid & 63;
  const int l15 = lane & 15, g = lane >> 4;
  const int bx = blockIdx.x;
  const int swzb = (bx & 7) * 512 + (bx >> 3);
  const int m0 = (swzb >> 3) * 128, n0 = (swzb & 7) * 128;
  const int wm = (wave >> 1) * 64, wn = (wave & 1) * 64;
  const int srow = lane >> 3;
  const int swslot = (lane & 7) ^ srow;

  f32x4 acc[4][4];
#pragma unroll
  for (int i = 0; i < 4; i++)
#pragma unroll
    for (int j = 0; j < 4; j++) acc[i][j] = (f32x4){0.f, 0.f, 0.f, 0.f};

  G1_PIPELINE();

  char* wb = lds + wave * 9216;
#pragma unroll
  for (int j = 0; j < 4; ++j) {
    float4 bb = *reinterpret_cast<const float4*>(Bb + n0 + wn + j * 16 + g * 4);
#pragma unroll
    for (int i = 0; i < 4; ++i) {
      ushort4 w;
      w.x = f2bf(acc[i][j][0] + bb.x);
      w.y = f2bf(acc[i][j][1] + bb.y);
      w.z = f2bf(acc[i][j][2] + bb.z);
      w.w = f2bf(acc[i][j][3] + bb.w);
      *reinterpret_cast<ushort4*>(wb + (i * 16 + l15) * 144 + j * 32 + g * 8) = w;
    }
  }
#pragma unroll
  for (int tt = 0; tt < 8; ++tt) {
    int ml = (lane >> 3) + tt * 8;
    int4 v = *reinterpret_cast<const int4*>(wb + ml * 144 + (lane & 7) * 16);
    int m = m0 + wm + ml;  // m = t*32 + batch
    size_t dst = ((size_t)(m & 31) * 2048 + (size_t)(m >> 5)) * HID +
                 n0 + wn + (lane & 7) * 8;
    *reinterpret_cast<int4*>(bout + dst) = v;
  }
}

// ------------- K2a (tier-2 only): per-chunk partial scan sums -----------
__global__ __launch_bounds__(256) void k_scan_partial(
    const unsigned short* __restrict__ b2, const float* __restrict__ A_log,
    float* __restrict__ Sbuf) {
  int gid = blockIdx.x * 256 + threadIdx.x;
  int ch = (gid & 4095) * 8;
  int c = gid >> 12;
  int bb = ch >> 10;
  int hh = ch & 1023;
  float4 al0 = *reinterpret_cast<const float4*>(A_log + hh);
  float4 al1 = *reinterpret_cast<const float4*>(A_log + hh + 4);
  float a[8] = {__expf(al0.x), __expf(al0.y), __expf(al0.z), __expf(al0.w),
                __expf(al1.x), __expf(al1.y), __expf(al1.z), __expf(al1.w)};
  const unsigned short* p = b2 + (size_t)bb * 2097152 + (size_t)c * CHUNK * HID + hh;
  float s[8] = {0.f, 0.f, 0.f, 0.f, 0.f, 0.f, 0.f, 0.f};
#pragma unroll 4
  for (int j = 0; j < CHUNK; ++j) {
    int4 v = *reinterpret_cast<const int4*>(p + (size_t)j * HID);
    unsigned int u[4] = {(unsigned)v.x, (unsigned)v.y, (unsigned)v.z, (unsigned)v.w};
#pragma unroll
    for (int e = 0; e < 4; ++e) {
      s[2 * e]     = fmaf(a[2 * e],     s[2 * e],     __uint_as_float(u[e] << 16));
      s[2 * e + 1] = fmaf(a[2 * e + 1], s[2 * e + 1], __uint_as_float(u[e] & 0xFFFF0000u));
    }
  }
  float4 o0 = {s[0], s[1], s[2], s[3]}, o1 = {s[4], s[5], s[6], s[7]};
  *reinterpret_cast<float4*>(Sbuf + (size_t)c * NCH + ch) = o0;
  *reinterpret_cast<float4*>(Sbuf + (size_t)c * NCH + ch + 4) = o1;
}

// ------------- K2b: carry scan (separate-buffer, tier-2) ----------------
__global__ __launch_bounds__(256) void k_scan_carry(
    const float* __restrict__ Sbuf, const float* __restrict__ A_log,
    float* __restrict__ Cbuf) {
  int ch = blockIdx.x * 256 + threadIdx.x;
  float aL = __expf(A_log[ch & (HID - 1)] * (float)CHUNK);
  float h = 0.f;
  for (int c = 0; c < NCHUNK; ++c) {
    Cbuf[(size_t)c * NCH + ch] = h;
    h = fmaf(aL, h, Sbuf[(size_t)c * NCH + ch]);
  }
}

// ------------- K2b': in-place carry (tier-1): S[c] -> C[c] ----------------
__global__ __launch_bounds__(256) void k_scan_carry_ip(
    float* __restrict__ SC, const float* __restrict__ A_log) {
  int ch = blockIdx.x * 256 + threadIdx.x;
  float aL = __expf(A_log[ch & (HID - 1)] * (float)CHUNK);
  float h = 0.f;
  for (int c = 0; c < NCHUNK; ++c) {
    float tmp = SC[(size_t)c * NCH + ch];
    SC[(size_t)c * NCH + ch] = h;
    h = fmaf(aL, h, tmp);
  }
}

// ---- K3 (shared, r7 verbatim): scan+tanh + mus GEMM + log-prob ----
__global__ __launch_bounds__(256) void k_gemm2f(
    const unsigned short* __restrict__ b2, const float* __restrict__ actions,
    const unsigned short* __restrict__ cwb, const float* __restrict__ Cb,
    const float* __restrict__ log_std, const float* __restrict__ A_log,
    const float* __restrict__ Cbuf, float* __restrict__ out) {
  __shared__ char lds[49152];  // 3 bufs x {A(8K)|B(8K)}
  const int tid = threadIdx.x;
  const int wave = tid >> 6, lane = tid & 63;
  const int l15 = lane & 15, g = lane >> 4;
  const int bq = blockIdx.x;
  const int bb = bq >> 5;
  const int t0 = (bq & 31) * 64;
  const int c0 = t0 >> 4;
  const int wm = wave * 16;
  const int srow = lane >> 3;
  const int swslot = (lane & 7) ^ srow;
  const int sh = tid & 63;
  const int tq = tid >> 6;

  const unsigned short* srcBase =
      b2 + (size_t)bb * 2097152 + (size_t)(t0 + tq * 16) * HID;
  const float* cbBase = Cbuf + (size_t)(c0 + tq) * NCH + bb * 1024;

  f32x4 acc[4];
#pragma unroll
  for (int j = 0; j < 4; j++) acc[j] = (f32x4){0.f, 0.f, 0.f, 0.f};

  unsigned short va[16];
  float a_cur, h_cur, a_nxt = 0.f, h_nxt = 0.f;
  {
#pragma unroll
    for (int p = 0; p < 2; ++p) {
      int chunk = wave * 2 + p;
      GLDS16((const char*)cwb + ((size_t)(chunk * 8 + srow)) * 2048 +
                 swslot * 16,
             lds + 8192 + chunk * 1024);
    }
    a_cur = A_log[sh];
    h_cur = cbBase[sh];
#pragma unroll
    for (int j = 0; j < 16; ++j) va[j] = srcBase[(size_t)j * HID + sh];
  }

#pragma unroll
  for (int kt = 0; kt < 16; ++kt) {
    char* buf = lds + (kt % 3) * 16384;
    {
      float a = fast_exp2(a_cur * LOG2E);
      float hst = h_cur;
#pragma unroll
      for (int j = 0; j < 16; ++j) {
        hst = fmaf(a, hst, bf2f(va[j]));
        float e = fast_exp2(hst * (2.0f * LOG2E));
        float tn = fmaf(-2.0f, fast_rcp(e + 1.0f), 1.0f);
        int row = tq * 16 + j;
        *reinterpret_cast<unsigned short*>(
            buf + row * 128 + ((sh * 2) ^ ((row & 7) << 4))) = f2bf(tn);
      }
    }
    if (kt < 15) {
      char* nbuf = lds + ((kt + 1) % 3) * 16384;
#pragma unroll
      for (int p = 0; p < 2; ++p) {
        int chunk = wave * 2 + p;
        GLDS16((const char*)cwb + ((size_t)(chunk * 8 + srow)) * 2048 +
                   (kt + 1) * 128 + swslot * 16,
               nbuf + 8192 + chunk * 1024);
      }
      const int hg2 = (kt + 1) * 64 + sh;
      a_nxt = A_log[hg2];
      h_nxt = cbBase[hg2];
#pragma unroll
      for (int j = 0; j < 16; ++j) va[j] = srcBase[(size_t)j * HID + hg2];
    }
    __builtin_amdgcn_sched_barrier(0);
    asm volatile("s_waitcnt vmcnt(20)" ::: "memory");
    asm volatile("s_waitcnt lgkmcnt(0)" ::: "memory");
    __builtin_amdgcn_s_barrier();
    __builtin_amdgcn_sched_barrier(0);
    bf16x8 af[2], bfv[4][2];
#pragma unroll
    for (int kk = 0; kk < 2; ++kk) {
      int slotsw = ((kk * 4 + g) ^ (l15 & 7)) * 16;
      af[kk] = *reinterpret_cast<const bf16x8*>(buf + (wm + l15) * 128 + slotsw);
#pragma unroll
      for (int f = 0; f < 4; ++f)
        bfv[f][kk] = *reinterpret_cast<const bf16x8*>(
            buf + 8192 + (f * 16 + l15) * 128 + slotsw);
    }
#pragma unroll
    for (int kk = 0; kk < 2; ++kk)
#pragma unroll
      for (int j = 0; j < 4; ++j)
        acc[j] = __builtin_amdgcn_mfma_f32_16x16x32_bf16(
            af[kk], bfv[j][kk], acc[j], 0, 0, 0);
    a_cur = a_nxt;
    h_cur = h_nxt;
  }
  float istd[4], cb[4];
#pragma unroll
  for (int j = 0; j < 4; ++j) {
    int n = j * 16 + l15;
    istd[j] = __expf(-log_std[n]);
    cb[j] = Cb[n];
  }
  float sls = 0.f;
  for (int n = 0; n < ADIM; ++n) sls += log_std[n];
  const float cterm = -32.0f * 1.8378770664093453f - sls;
  const int rb = wm + g * 4;
#pragma unroll
  for (int r = 0; r < 4; ++r) {
    int rl = rb + r;
    int mo = (t0 + rl) * 32 + bb;
    float ss = 0.f;
#pragma unroll
    for (int j = 0; j < 4; ++j) {
      int n = j * 16 + l15;
      float mu = acc[j][r] + cb[j];
      float d = (actions[(size_t)mo * ADIM + n] - mu) * istd[j];
      ss = fmaf(d, d, ss);
    }
    ss += __shfl_xor(ss, 1);
    ss += __shfl_xor(ss, 2);
    ss += __shfl_xor(ss, 4);
    ss += __shfl_xor(ss, 8);
    if (l15 == 0) out[mo] = cterm - 0.5f * ss;
  }
}

extern "C" void kernel_launch(void* const* d_in, const int* in_sizes, int n_in,
                              void* d_out, int out_size, void* d_ws, size_t ws_size,
                              hipStream_t stream) {
  const float* states  = (const float*)d_in[0];
  const float* actions = (const float*)d_in[1];
  const float* A_log   = (const float*)d_in[2];
  const float* B_w     = (const float*)d_in[3];
  const float* B_b     = (const float*)d_in[4];
  const float* C_w     = (const float*)d_in[5];
  const float* C_b     = (const float*)d_in[6];
  const float* log_std = (const float*)d_in[7];
  float* out = (float*)d_out;
  char* ws = (char*)d_ws;

  unsigned short* bbuf = (unsigned short*)ws;
  unsigned short* stb = (unsigned short*)(ws + WS_STB);

  if (ws_size >= WS_NEED_F) {
    // tier-1: fused partials in gemm1p (m2-order), in-place carry
    float* SC = (float*)(ws + WS_SCB);
    unsigned short* bwb = (unsigned short*)(ws + WS_BWB_F);
    unsigned short* cwb = (unsigned short*)(ws + WS_CWB_F);
    k_cvt<<<8352, 256, 0, stream>>>(states, B_w, C_w, stb, bwb, cwb, 1);
    k_gemm1p_f<<<4096, 256, 0, stream>>>(stb, bwb, B_b, A_log, bbuf, SC);
    k_scan_carry_ip<<<128, 256, 0, stream>>>(SC, A_log);
    k_gemm2f<<<1024, 256, 0, stream>>>(bbuf, actions, cwb, C_b, log_std, A_log,
                                       SC, out);
  } else {
    // tier-2: round-7 proven path
    float* Sbuf = (float*)(ws + WS_SBUF2);
    float* Cbuf = (float*)(ws + WS_CBUF2);
    unsigned short* bwb = (unsigned short*)(ws + WS_BWB2);
    unsigned short* cwb = (unsigned short*)(ws + WS_CWB2);
    k_cvt<<<8352, 256, 0, stream>>>(states, B_w, C_w, stb, bwb, cwb, 0);
    k_gemm1p_7<<<4096, 256, 0, stream>>>(stb, bwb, B_b, bbuf);
    k_scan_partial<<<2048, 256, 0, stream>>>(bbuf, A_log, Sbuf);
    k_scan_carry<<<128, 256, 0, stream>>>(Sbuf, A_log, Cbuf);
    k_gemm2f<<<1024, 256, 0, stream>>>(bbuf, actions, cwb, C_b, log_std, A_log,
                                       Cbuf, out);
  }
}

// Round 10
// 139.288 us; speedup vs baseline: 2.2633x; 1.2578x over previous
//
#include <hip/hip_runtime.h>
#include <hip/hip_bf16.h>

typedef __attribute__((ext_vector_type(4))) float f32x4;
typedef __attribute__((ext_vector_type(8))) short bf16x8;

#define SDIM 256
#define HID 1024
#define ADIM 64
#define CHUNK 16
#define NCHUNK 128
#define NCH 32768  // BATCH * HID

// ws layout (both tiers): bbuf2 [0,128M) as [b][t][h]; stb [128M,160M)
// Tier-1 (fused): SCbuf [160M,176M); bwb/cwb after -> WS_NEED_F
// Tier-2 (r7):    Sbuf/Cbuf alias stb after gemm1p; bwb/cwb at 160M
#define WS_STB   134217728ull
#define WS_SCB   167772160ull
#define WS_BWB_F 184549376ull
#define WS_CWB_F 185073664ull
#define WS_NEED_F 185204736ull
// tier-2 (round-7 proven)
#define WS_SBUF2 134217728ull
#define WS_CBUF2 150994944ull
#define WS_BWB2  167772160ull
#define WS_CWB2  168296448ull
#define WS_NEED2 168427520ull

__device__ __forceinline__ unsigned short f2bf(float f) {
  unsigned int u = __float_as_uint(f);
  u += 0x7FFF + ((u >> 16) & 1);  // RNE
  return (unsigned short)(u >> 16);
}
__device__ __forceinline__ float bf2f(unsigned short h) {
  return __uint_as_float(((unsigned int)h) << 16);
}
__device__ __forceinline__ float fast_exp2(float x) {
  float r;
  asm volatile("v_exp_f32 %0, %1" : "=v"(r) : "v"(x));
  return r;
}
__device__ __forceinline__ float fast_rcp(float x) {
  float r;
  asm volatile("v_rcp_f32 %0, %1" : "=v"(r) : "v"(x));
  return r;
}
#define LOG2E 1.4426950408889634f

#define GLDS16(gp, lp)                                                        \
  __builtin_amdgcn_global_load_lds(                                           \
      (const __attribute__((address_space(1))) unsigned int*)(gp),            \
      (__attribute__((address_space(3))) unsigned int*)(lp), 16, 0, 0)

// ---------------- pre-convert fp32 -> bf16 (states, B_w, C_w) --------------
// perm=1: write states rows in m2-order (batch-major: m2=(m&31)*2048+(m>>5))
#define CVT_SN 16777216
#define CVT_BN 262144
#define CVT_CN 65536
__global__ __launch_bounds__(256) void k_cvt(
    const float* __restrict__ s, const float* __restrict__ bw,
    const float* __restrict__ cw, unsigned short* __restrict__ sb,
    unsigned short* __restrict__ bwb, unsigned short* __restrict__ cwb,
    int perm) {
  long long f = ((long long)blockIdx.x * 256 + threadIdx.x) * 8;
  const float* src;
  unsigned short* dst;
  long long idx, didx;
  if (f < CVT_SN) {
    src = s; dst = sb; idx = f;
    if (perm) {
      long long m = f >> 8, col = f & 255;
      didx = ((m & 31) * 2048 + (m >> 5)) * 256 + col;
    } else didx = f;
  } else if (f < CVT_SN + CVT_BN) {
    src = bw; dst = bwb; idx = f - CVT_SN; didx = idx;
  } else {
    src = cw; dst = cwb; idx = f - CVT_SN - CVT_BN; didx = idx;
  }
  float4 a = *reinterpret_cast<const float4*>(src + idx);
  float4 b = *reinterpret_cast<const float4*>(src + idx + 4);
  ushort4 lo, hi;
  lo.x = f2bf(a.x); lo.y = f2bf(a.y); lo.z = f2bf(a.z); lo.w = f2bf(a.w);
  hi.x = f2bf(b.x); hi.y = f2bf(b.y); hi.z = f2bf(b.z); hi.w = f2bf(b.w);
  *reinterpret_cast<ushort4*>(dst + didx) = lo;
  *reinterpret_cast<ushort4*>(dst + didx + 4) = hi;
}

// -------------------- shared GEMM1 compute (r4/r7 proven) ------------------
__device__ __forceinline__ void g1_compute(
    const char* bA, const char* bB, f32x4 (&acc)[4][4],
    int wm, int wn, int l15, int g) {
  bf16x8 af[4][2], bfv[4][2];
#pragma unroll
  for (int kk = 0; kk < 2; ++kk) {
    int slotsw = ((kk * 4 + g) ^ (l15 & 7)) * 16;
#pragma unroll
    for (int f = 0; f < 4; ++f) {
      af[f][kk] = *reinterpret_cast<const bf16x8*>(bA + (wm + f * 16 + l15) * 128 + slotsw);
      bfv[f][kk] = *reinterpret_cast<const bf16x8*>(bB + (wn + f * 16 + l15) * 128 + slotsw);
    }
  }
#pragma unroll
  for (int kk = 0; kk < 2; ++kk)
#pragma unroll
    for (int i = 0; i < 4; ++i)
#pragma unroll
      for (int j = 0; j < 4; ++j)
        acc[i][j] = __builtin_amdgcn_mfma_f32_16x16x32_bf16(
            bfv[j][kk], af[i][kk], acc[i][j], 0, 0, 0);
}

#define STAGE1(tile, buf)                                                     \
  {                                                                           \
    const int k0b_ = (tile) * 128;                                            \
    char* dA_ = lds + (buf) * 32768;                                          \
    char* dB_ = lds + 16384 + (buf) * 32768;                                  \
    _Pragma("unroll")                                                         \
    for (int p = 0; p < 4; ++p) {                                             \
      int chunk = wave * 4 + p;                                               \
      GLDS16((const char*)sb + ((size_t)(m0 + chunk * 8 + srow) * SDIM) * 2 + \
                 k0b_ + swslot * 16,                                          \
             dA_ + chunk * 1024);                                             \
      GLDS16((const char*)bwb + ((size_t)(n0 + chunk * 8 + srow) * SDIM) * 2 +\
                 k0b_ + swslot * 16,                                          \
             dB_ + chunk * 1024);                                             \
    }                                                                         \
  }

#define G1_PIPELINE()                                                         \
  STAGE1(0, 0);                                                               \
  for (int t = 0; t < 3; ++t) {                                               \
    const int cur = t & 1;                                                    \
    STAGE1(t + 1, cur ^ 1);                                                   \
    asm volatile("s_waitcnt vmcnt(8)" ::: "memory");                          \
    __builtin_amdgcn_s_barrier();                                             \
    __builtin_amdgcn_sched_barrier(0);                                        \
    g1_compute(lds + cur * 32768, lds + 16384 + cur * 32768, acc, wm, wn,     \
               l15, g);                                                       \
    __builtin_amdgcn_s_barrier();                                             \
    __builtin_amdgcn_sched_barrier(0);                                        \
  }                                                                           \
  asm volatile("s_waitcnt vmcnt(0)" ::: "memory");                            \
  __builtin_amdgcn_s_barrier();                                               \
  __builtin_amdgcn_sched_barrier(0);                                          \
  g1_compute(lds + 32768, lds + 16384 + 32768, acc, wm, wn, l15, g);          \
  __builtin_amdgcn_s_barrier();                                               \
  __builtin_amdgcn_sched_barrier(0);

// ---- K1 tier-1: b = states@B_w^T+B_b -> bbuf2 (m2-order tiles) ----
// r7 staging/MFMA; epilogue store loop ALSO emits per-16t chunk partials
// (replaces k_scan_partial) with batched 3-step shfl reduce over lane>>3.
__global__ __launch_bounds__(256) void k_gemm1p_f(
    const unsigned short* __restrict__ sb, const unsigned short* __restrict__ bwb,
    const float* __restrict__ Bb, const float* __restrict__ A_log,
    unsigned short* __restrict__ bout, float* __restrict__ Sb) {
  __shared__ char lds[65536];
  const int tid = threadIdx.x;
  const int wave = tid >> 6, lane = tid & 63;
  const int l15 = lane & 15, g = lane >> 4;
  const int bx = blockIdx.x;
  const int swzb = (bx & 7) * 512 + (bx >> 3);  // bijective XCD swizzle
  const int mt = swzb >> 3, nt = swzb & 7;
  const int m0 = mt * 128, n0 = nt * 128;  // m0 = m2-row base (batch-major)
  const int bb2 = mt >> 4;                 // batch of this tile
  const int c0t = (mt & 15) * 8;           // global t-chunk base
  const int wm = (wave >> 1) * 64, wn = (wave & 1) * 64;
  const int srow = lane >> 3;
  const int swslot = (lane & 7) ^ srow;

  f32x4 acc[4][4];
#pragma unroll
  for (int i = 0; i < 4; i++)
#pragma unroll
    for (int j = 0; j < 4; j++) acc[i][j] = (f32x4){0.f, 0.f, 0.f, 0.f};

  G1_PIPELINE();

  // epilogue part 1: bias + pack, per-wave LDS transpose (r7 verbatim)
  char* wb = lds + wave * 9216;
#pragma unroll
  for (int j = 0; j < 4; ++j) {
    float4 bb = *reinterpret_cast<const float4*>(Bb + n0 + wn + j * 16 + g * 4);
#pragma unroll
    for (int i = 0; i < 4; ++i) {
      ushort4 w;
      w.x = f2bf(acc[i][j][0] + bb.x);
      w.y = f2bf(acc[i][j][1] + bb.y);
      w.z = f2bf(acc[i][j][2] + bb.z);
      w.w = f2bf(acc[i][j][3] + bb.w);
      *reinterpret_cast<ushort4*>(wb + (i * 16 + l15) * 144 + j * 32 + g * 8) = w;
    }
  }
  // epilogue part 2: coalesced store + integrated chunk partials.
  // Thread owns h = n0+wn+(lane&7)*8 + e; rows ml = (lane>>3)+tt*8.
  // Chunk c uses tt = {2c, 2c+1}; reduce over lane>>3 (masks 8,16,32).
  const int h8 = lane & 7;
  float al8[8];
  {
    float4 a0 = *reinterpret_cast<const float4*>(A_log + n0 + wn + h8 * 8);
    float4 a1 = *reinterpret_cast<const float4*>(A_log + n0 + wn + h8 * 8 + 4);
    al8[0] = a0.x * LOG2E; al8[1] = a0.y * LOG2E;
    al8[2] = a0.z * LOG2E; al8[3] = a0.w * LOG2E;
    al8[4] = a1.x * LOG2E; al8[5] = a1.y * LOG2E;
    al8[6] = a1.z * LOG2E; al8[7] = a1.w * LOG2E;
  }
#pragma unroll
  for (int c = 0; c < 4; ++c) {
    float s8[8] = {0.f, 0.f, 0.f, 0.f, 0.f, 0.f, 0.f, 0.f};
#pragma unroll
    for (int ttp = 0; ttp < 2; ++ttp) {
      int tt = c * 2 + ttp;
      int ml = (lane >> 3) + tt * 8;
      int4 v = *reinterpret_cast<const int4*>(wb + ml * 144 + h8 * 16);
      *reinterpret_cast<int4*>(bout + (size_t)(m0 + wm + ml) * HID + n0 + wn +
                               h8 * 8) = v;
      const float wexp = (float)(15 - (ml & 15));
      unsigned int u[4] = {(unsigned)v.x, (unsigned)v.y, (unsigned)v.z,
                           (unsigned)v.w};
#pragma unroll
      for (int e = 0; e < 8; ++e) {
        unsigned int bits = (e & 1) ? (u[e >> 1] & 0xFFFF0000u) : (u[e >> 1] << 16);
        s8[e] = fmaf(__uint_as_float(bits), fast_exp2(al8[e] * wexp), s8[e]);
      }
    }
    // batched butterfly over lane bits 3,4,5 (8 independent swizzles/step)
#pragma unroll
    for (int mk = 8; mk <= 32; mk <<= 1) {
      float t[8];
#pragma unroll
      for (int e = 0; e < 8; ++e) t[e] = __shfl_xor(s8[e], mk);
#pragma unroll
      for (int e = 0; e < 8; ++e) s8[e] += t[e];
    }
    if ((lane & 56) == 0) {
      int cg = c0t + (wm >> 4) + c;
      float4 o0 = {s8[0], s8[1], s8[2], s8[3]};
      float4 o1 = {s8[4], s8[5], s8[6], s8[7]};
      float* sp = Sb + (size_t)cg * NCH + bb2 * 1024 + n0 + wn + h8 * 8;
      *reinterpret_cast<float4*>(sp) = o0;
      *reinterpret_cast<float4*>(sp + 4) = o1;
    }
  }
}

// ---- K1 tier-2: r7 verbatim (m-order tiles, permuted store) ----
__global__ __launch_bounds__(256) void k_gemm1p_7(
    const unsigned short* __restrict__ sb, const unsigned short* __restrict__ bwb,
    const float* __restrict__ Bb, unsigned short* __restrict__ bout) {
  __shared__ char lds[65536];
  const int tid = threadIdx.x;
  const int wave = tid >> 6, lane = tid & 63;
  const int l15 = lane & 15, g = lane >> 4;
  const int bx = blockIdx.x;
  const int swzb = (bx & 7) * 512 + (bx >> 3);
  const int m0 = (swzb >> 3) * 128, n0 = (swzb & 7) * 128;
  const int wm = (wave >> 1) * 64, wn = (wave & 1) * 64;
  const int srow = lane >> 3;
  const int swslot = (lane & 7) ^ srow;

  f32x4 acc[4][4];
#pragma unroll
  for (int i = 0; i < 4; i++)
#pragma unroll
    for (int j = 0; j < 4; j++) acc[i][j] = (f32x4){0.f, 0.f, 0.f, 0.f};

  G1_PIPELINE();

  char* wb = lds + wave * 9216;
#pragma unroll
  for (int j = 0; j < 4; ++j) {
    float4 bb = *reinterpret_cast<const float4*>(Bb + n0 + wn + j * 16 + g * 4);
#pragma unroll
    for (int i = 0; i < 4; ++i) {
      ushort4 w;
      w.x = f2bf(acc[i][j][0] + bb.x);
      w.y = f2bf(acc[i][j][1] + bb.y);
      w.z = f2bf(acc[i][j][2] + bb.z);
      w.w = f2bf(acc[i][j][3] + bb.w);
      *reinterpret_cast<ushort4*>(wb + (i * 16 + l15) * 144 + j * 32 + g * 8) = w;
    }
  }
#pragma unroll
  for (int tt = 0; tt < 8; ++tt) {
    int ml = (lane >> 3) + tt * 8;
    int4 v = *reinterpret_cast<const int4*>(wb + ml * 144 + (lane & 7) * 16);
    int m = m0 + wm + ml;  // m = t*32 + batch
    size_t dst = ((size_t)(m & 31) * 2048 + (size_t)(m >> 5)) * HID +
                 n0 + wn + (lane & 7) * 8;
    *reinterpret_cast<int4*>(bout + dst) = v;
  }
}

// ------------- K2a (tier-2 only): per-chunk partial scan sums -----------
__global__ __launch_bounds__(256) void k_scan_partial(
    const unsigned short* __restrict__ b2, const float* __restrict__ A_log,
    float* __restrict__ Sbuf) {
  int gid = blockIdx.x * 256 + threadIdx.x;
  int ch = (gid & 4095) * 8;
  int c = gid >> 12;
  int bb = ch >> 10;
  int hh = ch & 1023;
  float4 al0 = *reinterpret_cast<const float4*>(A_log + hh);
  float4 al1 = *reinterpret_cast<const float4*>(A_log + hh + 4);
  float a[8] = {__expf(al0.x), __expf(al0.y), __expf(al0.z), __expf(al0.w),
                __expf(al1.x), __expf(al1.y), __expf(al1.z), __expf(al1.w)};
  const unsigned short* p = b2 + (size_t)bb * 2097152 + (size_t)c * CHUNK * HID + hh;
  float s[8] = {0.f, 0.f, 0.f, 0.f, 0.f, 0.f, 0.f, 0.f};
#pragma unroll 4
  for (int j = 0; j < CHUNK; ++j) {
    int4 v = *reinterpret_cast<const int4*>(p + (size_t)j * HID);
    unsigned int u[4] = {(unsigned)v.x, (unsigned)v.y, (unsigned)v.z, (unsigned)v.w};
#pragma unroll
    for (int e = 0; e < 4; ++e) {
      s[2 * e]     = fmaf(a[2 * e],     s[2 * e],     __uint_as_float(u[e] << 16));
      s[2 * e + 1] = fmaf(a[2 * e + 1], s[2 * e + 1], __uint_as_float(u[e] & 0xFFFF0000u));
    }
  }
  float4 o0 = {s[0], s[1], s[2], s[3]}, o1 = {s[4], s[5], s[6], s[7]};
  *reinterpret_cast<float4*>(Sbuf + (size_t)c * NCH + ch) = o0;
  *reinterpret_cast<float4*>(Sbuf + (size_t)c * NCH + ch + 4) = o1;
}

// ------------- K2b: carry scan (separate-buffer, tier-2) ----------------
__global__ __launch_bounds__(256) void k_scan_carry(
    const float* __restrict__ Sbuf, const float* __restrict__ A_log,
    float* __restrict__ Cbuf) {
  int ch = blockIdx.x * 256 + threadIdx.x;
  float aL = __expf(A_log[ch & (HID - 1)] * (float)CHUNK);
  float h = 0.f;
  for (int c = 0; c < NCHUNK; ++c) {
    Cbuf[(size_t)c * NCH + ch] = h;
    h = fmaf(aL, h, Sbuf[(size_t)c * NCH + ch]);
  }
}

// ------------- K2b': in-place carry (tier-1): S[c] -> C[c] ----------------
__global__ __launch_bounds__(256) void k_scan_carry_ip(
    float* __restrict__ SC, const float* __restrict__ A_log) {
  int ch = blockIdx.x * 256 + threadIdx.x;
  float aL = __expf(A_log[ch & (HID - 1)] * (float)CHUNK);
  float h = 0.f;
  for (int c = 0; c < NCHUNK; ++c) {
    float tmp = SC[(size_t)c * NCH + ch];
    SC[(size_t)c * NCH + ch] = h;
    h = fmaf(aL, h, tmp);
  }
}

// ---- K3 (shared, r7 verbatim): scan+tanh + mus GEMM + log-prob ----
__global__ __launch_bounds__(256) void k_gemm2f(
    const unsigned short* __restrict__ b2, const float* __restrict__ actions,
    const unsigned short* __restrict__ cwb, const float* __restrict__ Cb,
    const float* __restrict__ log_std, const float* __restrict__ A_log,
    const float* __restrict__ Cbuf, float* __restrict__ out) {
  __shared__ char lds[49152];  // 3 bufs x {A(8K)|B(8K)}
  const int tid = threadIdx.x;
  const int wave = tid >> 6, lane = tid & 63;
  const int l15 = lane & 15, g = lane >> 4;
  const int bq = blockIdx.x;
  const int bb = bq >> 5;
  const int t0 = (bq & 31) * 64;
  const int c0 = t0 >> 4;
  const int wm = wave * 16;
  const int srow = lane >> 3;
  const int swslot = (lane & 7) ^ srow;
  const int sh = tid & 63;
  const int tq = tid >> 6;

  const unsigned short* srcBase =
      b2 + (size_t)bb * 2097152 + (size_t)(t0 + tq * 16) * HID;
  const float* cbBase = Cbuf + (size_t)(c0 + tq) * NCH + bb * 1024;

  f32x4 acc[4];
#pragma unroll
  for (int j = 0; j < 4; j++) acc[j] = (f32x4){0.f, 0.f, 0.f, 0.f};

  unsigned short va[16];
  float a_cur, h_cur, a_nxt = 0.f, h_nxt = 0.f;
  {
#pragma unroll
    for (int p = 0; p < 2; ++p) {
      int chunk = wave * 2 + p;
      GLDS16((const char*)cwb + ((size_t)(chunk * 8 + srow)) * 2048 +
                 swslot * 16,
             lds + 8192 + chunk * 1024);
    }
    a_cur = A_log[sh];
    h_cur = cbBase[sh];
#pragma unroll
    for (int j = 0; j < 16; ++j) va[j] = srcBase[(size_t)j * HID + sh];
  }

#pragma unroll
  for (int kt = 0; kt < 16; ++kt) {
    char* buf = lds + (kt % 3) * 16384;
    {
      float a = fast_exp2(a_cur * LOG2E);
      float hst = h_cur;
#pragma unroll
      for (int j = 0; j < 16; ++j) {
        hst = fmaf(a, hst, bf2f(va[j]));
        float e = fast_exp2(hst * (2.0f * LOG2E));
        float tn = fmaf(-2.0f, fast_rcp(e + 1.0f), 1.0f);
        int row = tq * 16 + j;
        *reinterpret_cast<unsigned short*>(
            buf + row * 128 + ((sh * 2) ^ ((row & 7) << 4))) = f2bf(tn);
      }
    }
    if (kt < 15) {
      char* nbuf = lds + ((kt + 1) % 3) * 16384;
#pragma unroll
      for (int p = 0; p < 2; ++p) {
        int chunk = wave * 2 + p;
        GLDS16((const char*)cwb + ((size_t)(chunk * 8 + srow)) * 2048 +
                   (kt + 1) * 128 + swslot * 16,
               nbuf + 8192 + chunk * 1024);
      }
      const int hg2 = (kt + 1) * 64 + sh;
      a_nxt = A_log[hg2];
      h_nxt = cbBase[hg2];
#pragma unroll
      for (int j = 0; j < 16; ++j) va[j] = srcBase[(size_t)j * HID + hg2];
    }
    __builtin_amdgcn_sched_barrier(0);
    asm volatile("s_waitcnt vmcnt(20)" ::: "memory");
    asm volatile("s_waitcnt lgkmcnt(0)" ::: "memory");
    __builtin_amdgcn_s_barrier();
    __builtin_amdgcn_sched_barrier(0);
    bf16x8 af[2], bfv[4][2];
#pragma unroll
    for (int kk = 0; kk < 2; ++kk) {
      int slotsw = ((kk * 4 + g) ^ (l15 & 7)) * 16;
      af[kk] = *reinterpret_cast<const bf16x8*>(buf + (wm + l15) * 128 + slotsw);
#pragma unroll
      for (int f = 0; f < 4; ++f)
        bfv[f][kk] = *reinterpret_cast<const bf16x8*>(
            buf + 8192 + (f * 16 + l15) * 128 + slotsw);
    }
#pragma unroll
    for (int kk = 0; kk < 2; ++kk)
#pragma unroll
      for (int j = 0; j < 4; ++j)
        acc[j] = __builtin_amdgcn_mfma_f32_16x16x32_bf16(
            af[kk], bfv[j][kk], acc[j], 0, 0, 0);
    a_cur = a_nxt;
    h_cur = h_nxt;
  }
  float istd[4], cb[4];
#pragma unroll
  for (int j = 0; j < 4; ++j) {
    int n = j * 16 + l15;
    istd[j] = __expf(-log_std[n]);
    cb[j] = Cb[n];
  }
  float sls = 0.f;
  for (int n = 0; n < ADIM; ++n) sls += log_std[n];
  const float cterm = -32.0f * 1.8378770664093453f - sls;
  const int rb = wm + g * 4;
#pragma unroll
  for (int r = 0; r < 4; ++r) {
    int rl = rb + r;
    int mo = (t0 + rl) * 32 + bb;
    float ss = 0.f;
#pragma unroll
    for (int j = 0; j < 4; ++j) {
      int n = j * 16 + l15;
      float mu = acc[j][r] + cb[j];
      float d = (actions[(size_t)mo * ADIM + n] - mu) * istd[j];
      ss = fmaf(d, d, ss);
    }
    ss += __shfl_xor(ss, 1);
    ss += __shfl_xor(ss, 2);
    ss += __shfl_xor(ss, 4);
    ss += __shfl_xor(ss, 8);
    if (l15 == 0) out[mo] = cterm - 0.5f * ss;
  }
}

extern "C" void kernel_launch(void* const* d_in, const int* in_sizes, int n_in,
                              void* d_out, int out_size, void* d_ws, size_t ws_size,
                              hipStream_t stream) {
  const float* states  = (const float*)d_in[0];
  const float* actions = (const float*)d_in[1];
  const float* A_log   = (const float*)d_in[2];
  const float* B_w     = (const float*)d_in[3];
  const float* B_b     = (const float*)d_in[4];
  const float* C_w     = (const float*)d_in[5];
  const float* C_b     = (const float*)d_in[6];
  const float* log_std = (const float*)d_in[7];
  float* out = (float*)d_out;
  char* ws = (char*)d_ws;

  unsigned short* bbuf = (unsigned short*)ws;
  unsigned short* stb = (unsigned short*)(ws + WS_STB);

  if (ws_size >= WS_NEED_F) {
    // tier-1: fused partials in gemm1p epilogue (m2-order), in-place carry
    float* SC = (float*)(ws + WS_SCB);
    unsigned short* bwb = (unsigned short*)(ws + WS_BWB_F);
    unsigned short* cwb = (unsigned short*)(ws + WS_CWB_F);
    k_cvt<<<8352, 256, 0, stream>>>(states, B_w, C_w, stb, bwb, cwb, 1);
    k_gemm1p_f<<<4096, 256, 0, stream>>>(stb, bwb, B_b, A_log, bbuf, SC);
    k_scan_carry_ip<<<128, 256, 0, stream>>>(SC, A_log);
    k_gemm2f<<<1024, 256, 0, stream>>>(bbuf, actions, cwb, C_b, log_std, A_log,
                                       SC, out);
  } else {
    // tier-2: round-7 proven path
    float* Sbuf = (float*)(ws + WS_SBUF2);
    float* Cbuf = (float*)(ws + WS_CBUF2);
    unsigned short* bwb = (unsigned short*)(ws + WS_BWB2);
    unsigned short* cwb = (unsigned short*)(ws + WS_CWB2);
    k_cvt<<<8352, 256, 0, stream>>>(states, B_w, C_w, stb, bwb, cwb, 0);
    k_gemm1p_7<<<4096, 256, 0, stream>>>(stb, bwb, B_b, bbuf);
    k_scan_partial<<<2048, 256, 0, stream>>>(bbuf, A_log, Sbuf);
    k_scan_carry<<<128, 256, 0, stream>>>(Sbuf, A_log, Cbuf);
    k_gemm2f<<<1024, 256, 0, stream>>>(bbuf, actions, cwb, C_b, log_std, A_log,
                                       Cbuf, out);
  }
}

// Round 11
// 133.156 us; speedup vs baseline: 2.3675x; 1.0461x over previous
//
#include <hip/hip_runtime.h>
#include <hip/hip_bf16.h>

typedef __attribute__((ext_vector_type(4))) float f32x4;
typedef __attribute__((ext_vector_type(8))) short bf16x8;

#define SDIM 256
#define HID 1024
#define ADIM 64
#define CHUNK 16
#define NCHUNK 128
#define NCH 32768  // BATCH * HID

// ws layout (both tiers): bbuf2 [0,128M) as [b][t][h]; stb [128M,160M)
// Tier-1 (fused): SCbuf [160M,176M); bwb/cwb after -> WS_NEED_F
// Tier-2 (r7):    Sbuf/Cbuf alias stb after gemm1p; bwb/cwb at 160M
#define WS_STB   134217728ull
#define WS_SCB   167772160ull
#define WS_BWB_F 184549376ull
#define WS_CWB_F 185073664ull
#define WS_NEED_F 185204736ull
// tier-2 (round-7 proven)
#define WS_SBUF2 134217728ull
#define WS_CBUF2 150994944ull
#define WS_BWB2  167772160ull
#define WS_CWB2  168296448ull
#define WS_NEED2 168427520ull

__device__ __forceinline__ unsigned short f2bf(float f) {
  unsigned int u = __float_as_uint(f);
  u += 0x7FFF + ((u >> 16) & 1);  // RNE
  return (unsigned short)(u >> 16);
}
__device__ __forceinline__ float bf2f(unsigned short h) {
  return __uint_as_float(((unsigned int)h) << 16);
}
// pure (non-volatile): CSE-able, freely schedulable
__device__ __forceinline__ float fast_exp2(float x) {
  float r;
  asm("v_exp_f32 %0, %1" : "=v"(r) : "v"(x));
  return r;
}
__device__ __forceinline__ float fast_rcp(float x) {
  float r;
  asm("v_rcp_f32 %0, %1" : "=v"(r) : "v"(x));
  return r;
}
#define LOG2E 1.4426950408889634f

#define GLDS16(gp, lp)                                                        \
  __builtin_amdgcn_global_load_lds(                                           \
      (const __attribute__((address_space(1))) unsigned int*)(gp),            \
      (__attribute__((address_space(3))) unsigned int*)(lp), 16, 0, 0)

// ---------------- pre-convert fp32 -> bf16 (states, B_w, C_w) --------------
// perm=1: write states rows in m2-order (batch-major: m2=(m&31)*2048+(m>>5))
#define CVT_SN 16777216
#define CVT_BN 262144
#define CVT_CN 65536
__global__ __launch_bounds__(256) void k_cvt(
    const float* __restrict__ s, const float* __restrict__ bw,
    const float* __restrict__ cw, unsigned short* __restrict__ sb,
    unsigned short* __restrict__ bwb, unsigned short* __restrict__ cwb,
    int perm) {
  long long f = ((long long)blockIdx.x * 256 + threadIdx.x) * 8;
  const float* src;
  unsigned short* dst;
  long long idx, didx;
  if (f < CVT_SN) {
    src = s; dst = sb; idx = f;
    if (perm) {
      long long m = f >> 8, col = f & 255;
      didx = ((m & 31) * 2048 + (m >> 5)) * 256 + col;
    } else didx = f;
  } else if (f < CVT_SN + CVT_BN) {
    src = bw; dst = bwb; idx = f - CVT_SN; didx = idx;
  } else {
    src = cw; dst = cwb; idx = f - CVT_SN - CVT_BN; didx = idx;
  }
  float4 a = *reinterpret_cast<const float4*>(src + idx);
  float4 b = *reinterpret_cast<const float4*>(src + idx + 4);
  ushort4 lo, hi;
  lo.x = f2bf(a.x); lo.y = f2bf(a.y); lo.z = f2bf(a.z); lo.w = f2bf(a.w);
  hi.x = f2bf(b.x); hi.y = f2bf(b.y); hi.z = f2bf(b.z); hi.w = f2bf(b.w);
  *reinterpret_cast<ushort4*>(dst + didx) = lo;
  *reinterpret_cast<ushort4*>(dst + didx + 4) = hi;
}

// -------------------- shared GEMM1 compute (r4/r7 proven) ------------------
__device__ __forceinline__ void g1_compute(
    const char* bA, const char* bB, f32x4 (&acc)[4][4],
    int wm, int wn, int l15, int g) {
  bf16x8 af[4][2], bfv[4][2];
#pragma unroll
  for (int kk = 0; kk < 2; ++kk) {
    int slotsw = ((kk * 4 + g) ^ (l15 & 7)) * 16;
#pragma unroll
    for (int f = 0; f < 4; ++f) {
      af[f][kk] = *reinterpret_cast<const bf16x8*>(bA + (wm + f * 16 + l15) * 128 + slotsw);
      bfv[f][kk] = *reinterpret_cast<const bf16x8*>(bB + (wn + f * 16 + l15) * 128 + slotsw);
    }
  }
#pragma unroll
  for (int kk = 0; kk < 2; ++kk)
#pragma unroll
    for (int i = 0; i < 4; ++i)
#pragma unroll
      for (int j = 0; j < 4; ++j)
        acc[i][j] = __builtin_amdgcn_mfma_f32_16x16x32_bf16(
            bfv[j][kk], af[i][kk], acc[i][j], 0, 0, 0);
}

#define STAGE1(tile, buf)                                                     \
  {                                                                           \
    const int k0b_ = (tile) * 128;                                            \
    char* dA_ = lds + (buf) * 32768;                                          \
    char* dB_ = lds + 16384 + (buf) * 32768;                                  \
    _Pragma("unroll")                                                         \
    for (int p = 0; p < 4; ++p) {                                             \
      int chunk = wave * 4 + p;                                               \
      GLDS16((const char*)sb + ((size_t)(m0 + chunk * 8 + srow) * SDIM) * 2 + \
                 k0b_ + swslot * 16,                                          \
             dA_ + chunk * 1024);                                             \
      GLDS16((const char*)bwb + ((size_t)(n0 + chunk * 8 + srow) * SDIM) * 2 +\
                 k0b_ + swslot * 16,                                          \
             dB_ + chunk * 1024);                                             \
    }                                                                         \
  }

#define G1_PIPELINE()                                                         \
  STAGE1(0, 0);                                                               \
  for (int t = 0; t < 3; ++t) {                                               \
    const int cur = t & 1;                                                    \
    STAGE1(t + 1, cur ^ 1);                                                   \
    asm volatile("s_waitcnt vmcnt(8)" ::: "memory");                          \
    __builtin_amdgcn_s_barrier();                                             \
    __builtin_amdgcn_sched_barrier(0);                                        \
    g1_compute(lds + cur * 32768, lds + 16384 + cur * 32768, acc, wm, wn,     \
               l15, g);                                                       \
    __builtin_amdgcn_s_barrier();                                             \
    __builtin_amdgcn_sched_barrier(0);                                        \
  }                                                                           \
  asm volatile("s_waitcnt vmcnt(0)" ::: "memory");                            \
  __builtin_amdgcn_s_barrier();                                               \
  __builtin_amdgcn_sched_barrier(0);                                          \
  g1_compute(lds + 32768, lds + 16384 + 32768, acc, wm, wn, l15, g);          \
  __builtin_amdgcn_s_barrier();                                               \
  __builtin_amdgcn_sched_barrier(0);

// ---- K1 tier-1: b = states@B_w^T+B_b -> bbuf2 (m2-order tiles) ----
// r7 staging/MFMA; epilogue store loop ALSO emits per-16t chunk partials
// (replaces k_scan_partial). Weights hoisted: wexp takes only 2 values
// {15-lr, 7-lr} across all chunks -> 16 exp2/thread instead of 64.
__global__ __launch_bounds__(256) void k_gemm1p_f(
    const unsigned short* __restrict__ sb, const unsigned short* __restrict__ bwb,
    const float* __restrict__ Bb, const float* __restrict__ A_log,
    unsigned short* __restrict__ bout, float* __restrict__ Sb) {
  __shared__ char lds[65536];
  const int tid = threadIdx.x;
  const int wave = tid >> 6, lane = tid & 63;
  const int l15 = lane & 15, g = lane >> 4;
  const int bx = blockIdx.x;
  const int swzb = (bx & 7) * 512 + (bx >> 3);  // bijective XCD swizzle
  const int mt = swzb >> 3, nt = swzb & 7;
  const int m0 = mt * 128, n0 = nt * 128;  // m0 = m2-row base (batch-major)
  const int bb2 = mt >> 4;                 // batch of this tile
  const int c0t = (mt & 15) * 8;           // global t-chunk base
  const int wm = (wave >> 1) * 64, wn = (wave & 1) * 64;
  const int srow = lane >> 3;
  const int swslot = (lane & 7) ^ srow;

  f32x4 acc[4][4];
#pragma unroll
  for (int i = 0; i < 4; i++)
#pragma unroll
    for (int j = 0; j < 4; j++) acc[i][j] = (f32x4){0.f, 0.f, 0.f, 0.f};

  G1_PIPELINE();

  // epilogue part 1: bias + pack, per-wave LDS transpose (r7 verbatim)
  char* wb = lds + wave * 9216;
#pragma unroll
  for (int j = 0; j < 4; ++j) {
    float4 bb = *reinterpret_cast<const float4*>(Bb + n0 + wn + j * 16 + g * 4);
#pragma unroll
    for (int i = 0; i < 4; ++i) {
      ushort4 w;
      w.x = f2bf(acc[i][j][0] + bb.x);
      w.y = f2bf(acc[i][j][1] + bb.y);
      w.z = f2bf(acc[i][j][2] + bb.z);
      w.w = f2bf(acc[i][j][3] + bb.w);
      *reinterpret_cast<ushort4*>(wb + (i * 16 + l15) * 144 + j * 32 + g * 8) = w;
    }
  }
  // epilogue part 2: coalesced store + integrated chunk partials.
  // Thread owns h = n0+wn+(lane&7)*8 + e; rows ml = (lane>>3)+tt*8.
  // ml&15 = (lane>>3) + 8*ttp  -> only two weight vectors, hoisted.
  const int h8 = lane & 7;
  const int lr = lane >> 3;
  float w15[8], w7[8];
  {
    float4 a0 = *reinterpret_cast<const float4*>(A_log + n0 + wn + h8 * 8);
    float4 a1 = *reinterpret_cast<const float4*>(A_log + n0 + wn + h8 * 8 + 4);
    float al8[8] = {a0.x, a0.y, a0.z, a0.w, a1.x, a1.y, a1.z, a1.w};
    const float e15 = (float)(15 - lr) * LOG2E;
    const float e7  = (float)(7 - lr) * LOG2E;
#pragma unroll
    for (int e = 0; e < 8; ++e) {
      w15[e] = fast_exp2(al8[e] * e15);
      w7[e]  = fast_exp2(al8[e] * e7);
    }
  }
#pragma unroll
  for (int c = 0; c < 4; ++c) {
    float s8[8] = {0.f, 0.f, 0.f, 0.f, 0.f, 0.f, 0.f, 0.f};
#pragma unroll
    for (int ttp = 0; ttp < 2; ++ttp) {
      int tt = c * 2 + ttp;
      int ml = lr + tt * 8;
      int4 v = *reinterpret_cast<const int4*>(wb + ml * 144 + h8 * 16);
      *reinterpret_cast<int4*>(bout + (size_t)(m0 + wm + ml) * HID + n0 + wn +
                               h8 * 8) = v;
      const float* wv = ttp ? w7 : w15;
      unsigned int u[4] = {(unsigned)v.x, (unsigned)v.y, (unsigned)v.z,
                           (unsigned)v.w};
#pragma unroll
      for (int e = 0; e < 8; ++e) {
        unsigned int bits = (e & 1) ? (u[e >> 1] & 0xFFFF0000u) : (u[e >> 1] << 16);
        s8[e] = fmaf(__uint_as_float(bits), wv[e], s8[e]);
      }
    }
    // batched butterfly over lane bits 3,4,5 (8 independent swizzles/step)
#pragma unroll
    for (int mk = 8; mk <= 32; mk <<= 1) {
      float t[8];
#pragma unroll
      for (int e = 0; e < 8; ++e) t[e] = __shfl_xor(s8[e], mk);
#pragma unroll
      for (int e = 0; e < 8; ++e) s8[e] += t[e];
    }
    if ((lane & 56) == 0) {
      int cg = c0t + (wm >> 4) + c;
      float4 o0 = {s8[0], s8[1], s8[2], s8[3]};
      float4 o1 = {s8[4], s8[5], s8[6], s8[7]};
      float* sp = Sb + (size_t)cg * NCH + bb2 * 1024 + n0 + wn + h8 * 8;
      *reinterpret_cast<float4*>(sp) = o0;
      *reinterpret_cast<float4*>(sp + 4) = o1;
    }
  }
}

// ---- K1 tier-2: r7 verbatim (m-order tiles, permuted store) ----
__global__ __launch_bounds__(256) void k_gemm1p_7(
    const unsigned short* __restrict__ sb, const unsigned short* __restrict__ bwb,
    const float* __restrict__ Bb, unsigned short* __restrict__ bout) {
  __shared__ char lds[65536];
  const int tid = threadIdx.x;
  const int wave = tid >> 6, lane = tid & 63;
  const int l15 = lane & 15, g = lane >> 4;
  const int bx = blockIdx.x;
  const int swzb = (bx & 7) * 512 + (bx >> 3);
  const int m0 = (swzb >> 3) * 128, n0 = (swzb & 7) * 128;
  const int wm = (wave >> 1) * 64, wn = (wave & 1) * 64;
  const int srow = lane >> 3;
  const int swslot = (lane & 7) ^ srow;

  f32x4 acc[4][4];
#pragma unroll
  for (int i = 0; i < 4; i++)
#pragma unroll
    for (int j = 0; j < 4; j++) acc[i][j] = (f32x4){0.f, 0.f, 0.f, 0.f};

  G1_PIPELINE();

  char* wb = lds + wave * 9216;
#pragma unroll
  for (int j = 0; j < 4; ++j) {
    float4 bb = *reinterpret_cast<const float4*>(Bb + n0 + wn + j * 16 + g * 4);
#pragma unroll
    for (int i = 0; i < 4; ++i) {
      ushort4 w;
      w.x = f2bf(acc[i][j][0] + bb.x);
      w.y = f2bf(acc[i][j][1] + bb.y);
      w.z = f2bf(acc[i][j][2] + bb.z);
      w.w = f2bf(acc[i][j][3] + bb.w);
      *reinterpret_cast<ushort4*>(wb + (i * 16 + l15) * 144 + j * 32 + g * 8) = w;
    }
  }
#pragma unroll
  for (int tt = 0; tt < 8; ++tt) {
    int ml = (lane >> 3) + tt * 8;
    int4 v = *reinterpret_cast<const int4*>(wb + ml * 144 + (lane & 7) * 16);
    int m = m0 + wm + ml;  // m = t*32 + batch
    size_t dst = ((size_t)(m & 31) * 2048 + (size_t)(m >> 5)) * HID +
                 n0 + wn + (lane & 7) * 8;
    *reinterpret_cast<int4*>(bout + dst) = v;
  }
}

// ------------- K2a (tier-2 only): per-chunk partial scan sums -----------
__global__ __launch_bounds__(256) void k_scan_partial(
    const unsigned short* __restrict__ b2, const float* __restrict__ A_log,
    float* __restrict__ Sbuf) {
  int gid = blockIdx.x * 256 + threadIdx.x;
  int ch = (gid & 4095) * 8;
  int c = gid >> 12;
  int bb = ch >> 10;
  int hh = ch & 1023;
  float4 al0 = *reinterpret_cast<const float4*>(A_log + hh);
  float4 al1 = *reinterpret_cast<const float4*>(A_log + hh + 4);
  float a[8] = {__expf(al0.x), __expf(al0.y), __expf(al0.z), __expf(al0.w),
                __expf(al1.x), __expf(al1.y), __expf(al1.z), __expf(al1.w)};
  const unsigned short* p = b2 + (size_t)bb * 2097152 + (size_t)c * CHUNK * HID + hh;
  float s[8] = {0.f, 0.f, 0.f, 0.f, 0.f, 0.f, 0.f, 0.f};
#pragma unroll 4
  for (int j = 0; j < CHUNK; ++j) {
    int4 v = *reinterpret_cast<const int4*>(p + (size_t)j * HID);
    unsigned int u[4] = {(unsigned)v.x, (unsigned)v.y, (unsigned)v.z, (unsigned)v.w};
#pragma unroll
    for (int e = 0; e < 4; ++e) {
      s[2 * e]     = fmaf(a[2 * e],     s[2 * e],     __uint_as_float(u[e] << 16));
      s[2 * e + 1] = fmaf(a[2 * e + 1], s[2 * e + 1], __uint_as_float(u[e] & 0xFFFF0000u));
    }
  }
  float4 o0 = {s[0], s[1], s[2], s[3]}, o1 = {s[4], s[5], s[6], s[7]};
  *reinterpret_cast<float4*>(Sbuf + (size_t)c * NCH + ch) = o0;
  *reinterpret_cast<float4*>(Sbuf + (size_t)c * NCH + ch + 4) = o1;
}

// ------------- K2b: carry scan (separate-buffer, tier-2) ----------------
__global__ __launch_bounds__(256) void k_scan_carry(
    const float* __restrict__ Sbuf, const float* __restrict__ A_log,
    float* __restrict__ Cbuf) {
  int ch = blockIdx.x * 256 + threadIdx.x;
  float aL = __expf(A_log[ch & (HID - 1)] * (float)CHUNK);
  float h = 0.f;
  for (int c = 0; c < NCHUNK; ++c) {
    Cbuf[(size_t)c * NCH + ch] = h;
    h = fmaf(aL, h, Sbuf[(size_t)c * NCH + ch]);
  }
}

// ------------- K2b': in-place carry (tier-1): S[c] -> C[c] ----------------
__global__ __launch_bounds__(256) void k_scan_carry_ip(
    float* __restrict__ SC, const float* __restrict__ A_log) {
  int ch = blockIdx.x * 256 + threadIdx.x;
  float aL = __expf(A_log[ch & (HID - 1)] * (float)CHUNK);
  float h = 0.f;
  for (int c = 0; c < NCHUNK; ++c) {
    float tmp = SC[(size_t)c * NCH + ch];
    SC[(size_t)c * NCH + ch] = h;
    h = fmaf(aL, h, tmp);
  }
}

// ---- K3 (shared, r7 verbatim): scan+tanh + mus GEMM + log-prob ----
__global__ __launch_bounds__(256) void k_gemm2f(
    const unsigned short* __restrict__ b2, const float* __restrict__ actions,
    const unsigned short* __restrict__ cwb, const float* __restrict__ Cb,
    const float* __restrict__ log_std, const float* __restrict__ A_log,
    const float* __restrict__ Cbuf, float* __restrict__ out) {
  __shared__ char lds[49152];  // 3 bufs x {A(8K)|B(8K)}
  const int tid = threadIdx.x;
  const int wave = tid >> 6, lane = tid & 63;
  const int l15 = lane & 15, g = lane >> 4;
  const int bq = blockIdx.x;
  const int bb = bq >> 5;
  const int t0 = (bq & 31) * 64;
  const int c0 = t0 >> 4;
  const int wm = wave * 16;
  const int srow = lane >> 3;
  const int swslot = (lane & 7) ^ srow;
  const int sh = tid & 63;
  const int tq = tid >> 6;

  const unsigned short* srcBase =
      b2 + (size_t)bb * 2097152 + (size_t)(t0 + tq * 16) * HID;
  const float* cbBase = Cbuf + (size_t)(c0 + tq) * NCH + bb * 1024;

  f32x4 acc[4];
#pragma unroll
  for (int j = 0; j < 4; j++) acc[j] = (f32x4){0.f, 0.f, 0.f, 0.f};

  unsigned short va[16];
  float a_cur, h_cur, a_nxt = 0.f, h_nxt = 0.f;
  {
#pragma unroll
    for (int p = 0; p < 2; ++p) {
      int chunk = wave * 2 + p;
      GLDS16((const char*)cwb + ((size_t)(chunk * 8 + srow)) * 2048 +
                 swslot * 16,
             lds + 8192 + chunk * 1024);
    }
    a_cur = A_log[sh];
    h_cur = cbBase[sh];
#pragma unroll
    for (int j = 0; j < 16; ++j) va[j] = srcBase[(size_t)j * HID + sh];
  }

#pragma unroll
  for (int kt = 0; kt < 16; ++kt) {
    char* buf = lds + (kt % 3) * 16384;
    {
      float a = fast_exp2(a_cur * LOG2E);
      float hst = h_cur;
#pragma unroll
      for (int j = 0; j < 16; ++j) {
        hst = fmaf(a, hst, bf2f(va[j]));
        float e = fast_exp2(hst * (2.0f * LOG2E));
        float tn = fmaf(-2.0f, fast_rcp(e + 1.0f), 1.0f);
        int row = tq * 16 + j;
        *reinterpret_cast<unsigned short*>(
            buf + row * 128 + ((sh * 2) ^ ((row & 7) << 4))) = f2bf(tn);
      }
    }
    if (kt < 15) {
      char* nbuf = lds + ((kt + 1) % 3) * 16384;
#pragma unroll
      for (int p = 0; p < 2; ++p) {
        int chunk = wave * 2 + p;
        GLDS16((const char*)cwb + ((size_t)(chunk * 8 + srow)) * 2048 +
                   (kt + 1) * 128 + swslot * 16,
               nbuf + 8192 + chunk * 1024);
      }
      const int hg2 = (kt + 1) * 64 + sh;
      a_nxt = A_log[hg2];
      h_nxt = cbBase[hg2];
#pragma unroll
      for (int j = 0; j < 16; ++j) va[j] = srcBase[(size_t)j * HID + hg2];
    }
    __builtin_amdgcn_sched_barrier(0);
    asm volatile("s_waitcnt vmcnt(20)" ::: "memory");
    asm volatile("s_waitcnt lgkmcnt(0)" ::: "memory");
    __builtin_amdgcn_s_barrier();
    __builtin_amdgcn_sched_barrier(0);
    bf16x8 af[2], bfv[4][2];
#pragma unroll
    for (int kk = 0; kk < 2; ++kk) {
      int slotsw = ((kk * 4 + g) ^ (l15 & 7)) * 16;
      af[kk] = *reinterpret_cast<const bf16x8*>(buf + (wm + l15) * 128 + slotsw);
#pragma unroll
      for (int f = 0; f < 4; ++f)
        bfv[f][kk] = *reinterpret_cast<const bf16x8*>(
            buf + 8192 + (f * 16 + l15) * 128 + slotsw);
    }
#pragma unroll
    for (int kk = 0; kk < 2; ++kk)
#pragma unroll
      for (int j = 0; j < 4; ++j)
        acc[j] = __builtin_amdgcn_mfma_f32_16x16x32_bf16(
            af[kk], bfv[j][kk], acc[j], 0, 0, 0);
    a_cur = a_nxt;
    h_cur = h_nxt;
  }
  float istd[4], cb[4];
#pragma unroll
  for (int j = 0; j < 4; ++j) {
    int n = j * 16 + l15;
    istd[j] = __expf(-log_std[n]);
    cb[j] = Cb[n];
  }
  float sls = 0.f;
  for (int n = 0; n < ADIM; ++n) sls += log_std[n];
  const float cterm = -32.0f * 1.8378770664093453f - sls;
  const int rb = wm + g * 4;
#pragma unroll
  for (int r = 0; r < 4; ++r) {
    int rl = rb + r;
    int mo = (t0 + rl) * 32 + bb;
    float ss = 0.f;
#pragma unroll
    for (int j = 0; j < 4; ++j) {
      int n = j * 16 + l15;
      float mu = acc[j][r] + cb[j];
      float d = (actions[(size_t)mo * ADIM + n] - mu) * istd[j];
      ss = fmaf(d, d, ss);
    }
    ss += __shfl_xor(ss, 1);
    ss += __shfl_xor(ss, 2);
    ss += __shfl_xor(ss, 4);
    ss += __shfl_xor(ss, 8);
    if (l15 == 0) out[mo] = cterm - 0.5f * ss;
  }
}

extern "C" void kernel_launch(void* const* d_in, const int* in_sizes, int n_in,
                              void* d_out, int out_size, void* d_ws, size_t ws_size,
                              hipStream_t stream) {
  const float* states  = (const float*)d_in[0];
  const float* actions = (const float*)d_in[1];
  const float* A_log   = (const float*)d_in[2];
  const float* B_w     = (const float*)d_in[3];
  const float* B_b     = (const float*)d_in[4];
  const float* C_w     = (const float*)d_in[5];
  const float* C_b     = (const float*)d_in[6];
  const float* log_std = (const float*)d_in[7];
  float* out = (float*)d_out;
  char* ws = (char*)d_ws;

  unsigned short* bbuf = (unsigned short*)ws;
  unsigned short* stb = (unsigned short*)(ws + WS_STB);

  if (ws_size >= WS_NEED_F) {
    // tier-1: fused partials in gemm1p epilogue (m2-order), in-place carry
    float* SC = (float*)(ws + WS_SCB);
    unsigned short* bwb = (unsigned short*)(ws + WS_BWB_F);
    unsigned short* cwb = (unsigned short*)(ws + WS_CWB_F);
    k_cvt<<<8352, 256, 0, stream>>>(states, B_w, C_w, stb, bwb, cwb, 1);
    k_gemm1p_f<<<4096, 256, 0, stream>>>(stb, bwb, B_b, A_log, bbuf, SC);
    k_scan_carry_ip<<<128, 256, 0, stream>>>(SC, A_log);
    k_gemm2f<<<1024, 256, 0, stream>>>(bbuf, actions, cwb, C_b, log_std, A_log,
                                       SC, out);
  } else {
    // tier-2: round-7 proven path
    float* Sbuf = (float*)(ws + WS_SBUF2);
    float* Cbuf = (float*)(ws + WS_CBUF2);
    unsigned short* bwb = (unsigned short*)(ws + WS_BWB2);
    unsigned short* cwb = (unsigned short*)(ws + WS_CWB2);
    k_cvt<<<8352, 256, 0, stream>>>(states, B_w, C_w, stb, bwb, cwb, 0);
    k_gemm1p_7<<<4096, 256, 0, stream>>>(stb, bwb, B_b, bbuf);
    k_scan_partial<<<2048, 256, 0, stream>>>(bbuf, A_log, Sbuf);
    k_scan_carry<<<128, 256, 0, stream>>>(Sbuf, A_log, Cbuf);
    k_gemm2f<<<1024, 256, 0, stream>>>(bbuf, actions, cwb, C_b, log_std, A_log,
                                       Cbuf, out);
  }
}

// Round 12
// 123.215 us; speedup vs baseline: 2.5585x; 1.0807x over previous
//
#include <hip/hip_runtime.h>
#include <hip/hip_bf16.h>

typedef __attribute__((ext_vector_type(4))) float f32x4;
typedef __attribute__((ext_vector_type(8))) short bf16x8;

#define SDIM 256
#define HID 1024
#define ADIM 64
#define CHUNK 16
#define NCHUNK 128
#define NCH 32768  // BATCH * HID

// ws layout (both tiers): bbuf2 [0,128M) as [b][t][h]; stb [128M,160M)
// Tier-1 (fused): SCbuf [160M,176M); bwb/cwb after -> WS_NEED_F
// Tier-2 (r7):    Sbuf/Cbuf alias stb after gemm1p; bwb/cwb at 160M
#define WS_STB   134217728ull
#define WS_SCB   167772160ull
#define WS_BWB_F 184549376ull
#define WS_CWB_F 185073664ull
#define WS_NEED_F 185204736ull
// tier-2 (round-7 proven)
#define WS_SBUF2 134217728ull
#define WS_CBUF2 150994944ull
#define WS_BWB2  167772160ull
#define WS_CWB2  168296448ull
#define WS_NEED2 168427520ull

__device__ __forceinline__ unsigned short f2bf(float f) {
  unsigned int u = __float_as_uint(f);
  u += 0x7FFF + ((u >> 16) & 1);  // RNE
  return (unsigned short)(u >> 16);
}
__device__ __forceinline__ float bf2f(unsigned short h) {
  return __uint_as_float(((unsigned int)h) << 16);
}
// pure (non-volatile): CSE-able, freely schedulable
__device__ __forceinline__ float fast_exp2(float x) {
  float r;
  asm("v_exp_f32 %0, %1" : "=v"(r) : "v"(x));
  return r;
}
__device__ __forceinline__ float fast_rcp(float x) {
  float r;
  asm("v_rcp_f32 %0, %1" : "=v"(r) : "v"(x));
  return r;
}
#define LOG2E 1.4426950408889634f

#define GLDS16(gp, lp)                                                        \
  __builtin_amdgcn_global_load_lds(                                           \
      (const __attribute__((address_space(1))) unsigned int*)(gp),            \
      (__attribute__((address_space(3))) unsigned int*)(lp), 16, 0, 0)

// ---------------- pre-convert fp32 -> bf16 (states, B_w, C_w) --------------
// perm=1: write states rows in m2-order (batch-major: m2=(m&31)*2048+(m>>5))
#define CVT_SN 16777216
#define CVT_BN 262144
#define CVT_CN 65536
__global__ __launch_bounds__(256) void k_cvt(
    const float* __restrict__ s, const float* __restrict__ bw,
    const float* __restrict__ cw, unsigned short* __restrict__ sb,
    unsigned short* __restrict__ bwb, unsigned short* __restrict__ cwb,
    int perm) {
  long long f = ((long long)blockIdx.x * 256 + threadIdx.x) * 8;
  const float* src;
  unsigned short* dst;
  long long idx, didx;
  if (f < CVT_SN) {
    src = s; dst = sb; idx = f;
    if (perm) {
      long long m = f >> 8, col = f & 255;
      didx = ((m & 31) * 2048 + (m >> 5)) * 256 + col;
    } else didx = f;
  } else if (f < CVT_SN + CVT_BN) {
    src = bw; dst = bwb; idx = f - CVT_SN; didx = idx;
  } else {
    src = cw; dst = cwb; idx = f - CVT_SN - CVT_BN; didx = idx;
  }
  float4 a = *reinterpret_cast<const float4*>(src + idx);
  float4 b = *reinterpret_cast<const float4*>(src + idx + 4);
  ushort4 lo, hi;
  lo.x = f2bf(a.x); lo.y = f2bf(a.y); lo.z = f2bf(a.z); lo.w = f2bf(a.w);
  hi.x = f2bf(b.x); hi.y = f2bf(b.y); hi.z = f2bf(b.z); hi.w = f2bf(b.w);
  *reinterpret_cast<ushort4*>(dst + didx) = lo;
  *reinterpret_cast<ushort4*>(dst + didx + 4) = hi;
}

// -------------------- shared GEMM1 compute (r4/r7 proven) ------------------
__device__ __forceinline__ void g1_compute(
    const char* bA, const char* bB, f32x4 (&acc)[4][4],
    int wm, int wn, int l15, int g) {
  bf16x8 af[4][2], bfv[4][2];
#pragma unroll
  for (int kk = 0; kk < 2; ++kk) {
    int slotsw = ((kk * 4 + g) ^ (l15 & 7)) * 16;
#pragma unroll
    for (int f = 0; f < 4; ++f) {
      af[f][kk] = *reinterpret_cast<const bf16x8*>(bA + (wm + f * 16 + l15) * 128 + slotsw);
      bfv[f][kk] = *reinterpret_cast<const bf16x8*>(bB + (wn + f * 16 + l15) * 128 + slotsw);
    }
  }
#pragma unroll
  for (int kk = 0; kk < 2; ++kk)
#pragma unroll
    for (int i = 0; i < 4; ++i)
#pragma unroll
      for (int j = 0; j < 4; ++j)
        acc[i][j] = __builtin_amdgcn_mfma_f32_16x16x32_bf16(
            bfv[j][kk], af[i][kk], acc[i][j], 0, 0, 0);
}

#define STAGE1(tile, buf)                                                     \
  {                                                                           \
    const int k0b_ = (tile) * 128;                                            \
    char* dA_ = lds + (buf) * 32768;                                          \
    char* dB_ = lds + 16384 + (buf) * 32768;                                  \
    _Pragma("unroll")                                                         \
    for (int p = 0; p < 4; ++p) {                                             \
      int chunk = wave * 4 + p;                                               \
      GLDS16((const char*)sb + ((size_t)(m0 + chunk * 8 + srow) * SDIM) * 2 + \
                 k0b_ + swslot * 16,                                          \
             dA_ + chunk * 1024);                                             \
      GLDS16((const char*)bwb + ((size_t)(n0 + chunk * 8 + srow) * SDIM) * 2 +\
                 k0b_ + swslot * 16,                                          \
             dB_ + chunk * 1024);                                             \
    }                                                                         \
  }

#define G1_PIPELINE()                                                         \
  STAGE1(0, 0);                                                               \
  for (int t = 0; t < 3; ++t) {                                               \
    const int cur = t & 1;                                                    \
    STAGE1(t + 1, cur ^ 1);                                                   \
    asm volatile("s_waitcnt vmcnt(8)" ::: "memory");                          \
    __builtin_amdgcn_s_barrier();                                             \
    __builtin_amdgcn_sched_barrier(0);                                        \
    g1_compute(lds + cur * 32768, lds + 16384 + cur * 32768, acc, wm, wn,     \
               l15, g);                                                       \
    __builtin_amdgcn_s_barrier();                                             \
    __builtin_amdgcn_sched_barrier(0);                                        \
  }                                                                           \
  asm volatile("s_waitcnt vmcnt(0)" ::: "memory");                            \
  __builtin_amdgcn_s_barrier();                                               \
  __builtin_amdgcn_sched_barrier(0);                                          \
  g1_compute(lds + 32768, lds + 16384 + 32768, acc, wm, wn, l15, g);          \
  __builtin_amdgcn_s_barrier();                                               \
  __builtin_amdgcn_sched_barrier(0);

// ---- K1 tier-1: b = states@B_w^T+B_b -> bbuf2 (m2-order tiles) ----
// r7 staging/MFMA; epilogue ALSO emits per-16t chunk partials (replaces
// k_scan_partial). Horner form: lane-half owns 8 rows (pure FMA chain),
// scale low half by a^8, single shfl_xor(8) combine -> 8 shfl vs 96.
__global__ __launch_bounds__(256) void k_gemm1p_f(
    const unsigned short* __restrict__ sb, const unsigned short* __restrict__ bwb,
    const float* __restrict__ Bb, const float* __restrict__ A_log,
    unsigned short* __restrict__ bout, float* __restrict__ Sb) {
  __shared__ char lds[65536];
  const int tid = threadIdx.x;
  const int wave = tid >> 6, lane = tid & 63;
  const int l15 = lane & 15, g = lane >> 4;
  const int bx = blockIdx.x;
  const int swzb = (bx & 7) * 512 + (bx >> 3);  // bijective XCD swizzle
  const int mt = swzb >> 3, nt = swzb & 7;
  const int m0 = mt * 128, n0 = nt * 128;  // m0 = m2-row base (batch-major)
  const int bb2 = mt >> 4;                 // batch of this tile
  const int c0t = (mt & 15) * 8;           // global t-chunk base
  const int wm = (wave >> 1) * 64, wn = (wave & 1) * 64;
  const int srow = lane >> 3;
  const int swslot = (lane & 7) ^ srow;

  f32x4 acc[4][4];
#pragma unroll
  for (int i = 0; i < 4; i++)
#pragma unroll
    for (int j = 0; j < 4; j++) acc[i][j] = (f32x4){0.f, 0.f, 0.f, 0.f};

  G1_PIPELINE();

  // epilogue part 1: bias + pack, per-wave LDS transpose (r7 verbatim)
  char* wb = lds + wave * 9216;
#pragma unroll
  for (int j = 0; j < 4; ++j) {
    float4 bb = *reinterpret_cast<const float4*>(Bb + n0 + wn + j * 16 + g * 4);
#pragma unroll
    for (int i = 0; i < 4; ++i) {
      ushort4 w;
      w.x = f2bf(acc[i][j][0] + bb.x);
      w.y = f2bf(acc[i][j][1] + bb.y);
      w.z = f2bf(acc[i][j][2] + bb.z);
      w.w = f2bf(acc[i][j][3] + bb.w);
      *reinterpret_cast<ushort4*>(wb + (i * 16 + l15) * 144 + j * 32 + g * 8) = w;
    }
  }
  const int h8 = lane & 7;
  const int lr = lane >> 3;
  // epilogue part 2a: coalesced global store (r7 verbatim)
#pragma unroll
  for (int tt = 0; tt < 8; ++tt) {
    int ml = lr + tt * 8;
    int4 v = *reinterpret_cast<const int4*>(wb + ml * 144 + h8 * 16);
    *reinterpret_cast<int4*>(bout + (size_t)(m0 + wm + ml) * HID + n0 + wn +
                             h8 * 8) = v;
  }
  // epilogue part 2b: chunk partials via Horner.
  // Thread (h8, lr): chunk c = lr>>1, half = lr&1 owns rows half*8+j.
  // S[c][h] = sum_p a^(15-p) b_p ; half-sum = Horner(a), low half *= a^8.
  {
    const int c = lr >> 1, half = lr & 1;
    float a1v[8], a8v[8];
    {
      float4 a0 = *reinterpret_cast<const float4*>(A_log + n0 + wn + h8 * 8);
      float4 a1_ = *reinterpret_cast<const float4*>(A_log + n0 + wn + h8 * 8 + 4);
      float al8[8] = {a0.x, a0.y, a0.z, a0.w, a1_.x, a1_.y, a1_.z, a1_.w};
#pragma unroll
      for (int e = 0; e < 8; ++e) {
        a1v[e] = fast_exp2(al8[e] * LOG2E);
        a8v[e] = fast_exp2(al8[e] * (8.0f * LOG2E));
      }
    }
    float s8[8] = {0.f, 0.f, 0.f, 0.f, 0.f, 0.f, 0.f, 0.f};
#pragma unroll
    for (int j = 0; j < 8; ++j) {
      int ml = c * 16 + half * 8 + j;
      int4 v = *reinterpret_cast<const int4*>(wb + ml * 144 + h8 * 16);
      unsigned int u[4] = {(unsigned)v.x, (unsigned)v.y, (unsigned)v.z,
                           (unsigned)v.w};
#pragma unroll
      for (int e = 0; e < 8; ++e) {
        unsigned int bits = (e & 1) ? (u[e >> 1] & 0xFFFF0000u) : (u[e >> 1] << 16);
        s8[e] = fmaf(a1v[e], s8[e], __uint_as_float(bits));
      }
    }
    const float hsel = half ? 1.0f : 0.0f;
#pragma unroll
    for (int e = 0; e < 8; ++e) {
      float scale = hsel + (1.0f - hsel) * a8v[e];  // half?1:a^8, branchless
      s8[e] *= scale;
      s8[e] += __shfl_xor(s8[e], 8);
    }
    if (half == 0) {
      int cg = c0t + (wm >> 4) + c;
      float4 o0 = {s8[0], s8[1], s8[2], s8[3]};
      float4 o1 = {s8[4], s8[5], s8[6], s8[7]};
      float* sp = Sb + (size_t)cg * NCH + bb2 * 1024 + n0 + wn + h8 * 8;
      *reinterpret_cast<float4*>(sp) = o0;
      *reinterpret_cast<float4*>(sp + 4) = o1;
    }
  }
}

// ---- K1 tier-2: r7 verbatim (m-order tiles, permuted store) ----
__global__ __launch_bounds__(256) void k_gemm1p_7(
    const unsigned short* __restrict__ sb, const unsigned short* __restrict__ bwb,
    const float* __restrict__ Bb, unsigned short* __restrict__ bout) {
  __shared__ char lds[65536];
  const int tid = threadIdx.x;
  const int wave = tid >> 6, lane = tid & 63;
  const int l15 = lane & 15, g = lane >> 4;
  const int bx = blockIdx.x;
  const int swzb = (bx & 7) * 512 + (bx >> 3);
  const int m0 = (swzb >> 3) * 128, n0 = (swzb & 7) * 128;
  const int wm = (wave >> 1) * 64, wn = (wave & 1) * 64;
  const int srow = lane >> 3;
  const int swslot = (lane & 7) ^ srow;

  f32x4 acc[4][4];
#pragma unroll
  for (int i = 0; i < 4; i++)
#pragma unroll
    for (int j = 0; j < 4; j++) acc[i][j] = (f32x4){0.f, 0.f, 0.f, 0.f};

  G1_PIPELINE();

  char* wb = lds + wave * 9216;
#pragma unroll
  for (int j = 0; j < 4; ++j) {
    float4 bb = *reinterpret_cast<const float4*>(Bb + n0 + wn + j * 16 + g * 4);
#pragma unroll
    for (int i = 0; i < 4; ++i) {
      ushort4 w;
      w.x = f2bf(acc[i][j][0] + bb.x);
      w.y = f2bf(acc[i][j][1] + bb.y);
      w.z = f2bf(acc[i][j][2] + bb.z);
      w.w = f2bf(acc[i][j][3] + bb.w);
      *reinterpret_cast<ushort4*>(wb + (i * 16 + l15) * 144 + j * 32 + g * 8) = w;
    }
  }
#pragma unroll
  for (int tt = 0; tt < 8; ++tt) {
    int ml = (lane >> 3) + tt * 8;
    int4 v = *reinterpret_cast<const int4*>(wb + ml * 144 + (lane & 7) * 16);
    int m = m0 + wm + ml;  // m = t*32 + batch
    size_t dst = ((size_t)(m & 31) * 2048 + (size_t)(m >> 5)) * HID +
                 n0 + wn + (lane & 7) * 8;
    *reinterpret_cast<int4*>(bout + dst) = v;
  }
}

// ------------- K2a (tier-2 only): per-chunk partial scan sums -----------
__global__ __launch_bounds__(256) void k_scan_partial(
    const unsigned short* __restrict__ b2, const float* __restrict__ A_log,
    float* __restrict__ Sbuf) {
  int gid = blockIdx.x * 256 + threadIdx.x;
  int ch = (gid & 4095) * 8;
  int c = gid >> 12;
  int bb = ch >> 10;
  int hh = ch & 1023;
  float4 al0 = *reinterpret_cast<const float4*>(A_log + hh);
  float4 al1 = *reinterpret_cast<const float4*>(A_log + hh + 4);
  float a[8] = {__expf(al0.x), __expf(al0.y), __expf(al0.z), __expf(al0.w),
                __expf(al1.x), __expf(al1.y), __expf(al1.z), __expf(al1.w)};
  const unsigned short* p = b2 + (size_t)bb * 2097152 + (size_t)c * CHUNK * HID + hh;
  float s[8] = {0.f, 0.f, 0.f, 0.f, 0.f, 0.f, 0.f, 0.f};
#pragma unroll 4
  for (int j = 0; j < CHUNK; ++j) {
    int4 v = *reinterpret_cast<const int4*>(p + (size_t)j * HID);
    unsigned int u[4] = {(unsigned)v.x, (unsigned)v.y, (unsigned)v.z, (unsigned)v.w};
#pragma unroll
    for (int e = 0; e < 4; ++e) {
      s[2 * e]     = fmaf(a[2 * e],     s[2 * e],     __uint_as_float(u[e] << 16));
      s[2 * e + 1] = fmaf(a[2 * e + 1], s[2 * e + 1], __uint_as_float(u[e] & 0xFFFF0000u));
    }
  }
  float4 o0 = {s[0], s[1], s[2], s[3]}, o1 = {s[4], s[5], s[6], s[7]};
  *reinterpret_cast<float4*>(Sbuf + (size_t)c * NCH + ch) = o0;
  *reinterpret_cast<float4*>(Sbuf + (size_t)c * NCH + ch + 4) = o1;
}

// ------------- K2b: carry scan (separate-buffer, tier-2) ----------------
__global__ __launch_bounds__(256) void k_scan_carry(
    const float* __restrict__ Sbuf, const float* __restrict__ A_log,
    float* __restrict__ Cbuf) {
  int ch = blockIdx.x * 256 + threadIdx.x;
  float aL = __expf(A_log[ch & (HID - 1)] * (float)CHUNK);
  float h = 0.f;
  for (int c = 0; c < NCHUNK; ++c) {
    Cbuf[(size_t)c * NCH + ch] = h;
    h = fmaf(aL, h, Sbuf[(size_t)c * NCH + ch]);
  }
}

// ------------- K2b': in-place carry (tier-1): S[c] -> C[c] ----------------
__global__ __launch_bounds__(256) void k_scan_carry_ip(
    float* __restrict__ SC, const float* __restrict__ A_log) {
  int ch = blockIdx.x * 256 + threadIdx.x;
  float aL = __expf(A_log[ch & (HID - 1)] * (float)CHUNK);
  float h = 0.f;
  for (int c = 0; c < NCHUNK; ++c) {
    float tmp = SC[(size_t)c * NCH + ch];
    SC[(size_t)c * NCH + ch] = h;
    h = fmaf(aL, h, tmp);
  }
}

// ---- K3 (shared, r7 verbatim): scan+tanh + mus GEMM + log-prob ----
__global__ __launch_bounds__(256) void k_gemm2f(
    const unsigned short* __restrict__ b2, const float* __restrict__ actions,
    const unsigned short* __restrict__ cwb, const float* __restrict__ Cb,
    const float* __restrict__ log_std, const float* __restrict__ A_log,
    const float* __restrict__ Cbuf, float* __restrict__ out) {
  __shared__ char lds[49152];  // 3 bufs x {A(8K)|B(8K)}
  const int tid = threadIdx.x;
  const int wave = tid >> 6, lane = tid & 63;
  const int l15 = lane & 15, g = lane >> 4;
  const int bq = blockIdx.x;
  const int bb = bq >> 5;
  const int t0 = (bq & 31) * 64;
  const int c0 = t0 >> 4;
  const int wm = wave * 16;
  const int srow = lane >> 3;
  const int swslot = (lane & 7) ^ srow;
  const int sh = tid & 63;
  const int tq = tid >> 6;

  const unsigned short* srcBase =
      b2 + (size_t)bb * 2097152 + (size_t)(t0 + tq * 16) * HID;
  const float* cbBase = Cbuf + (size_t)(c0 + tq) * NCH + bb * 1024;

  f32x4 acc[4];
#pragma unroll
  for (int j = 0; j < 4; j++) acc[j] = (f32x4){0.f, 0.f, 0.f, 0.f};

  unsigned short va[16];
  float a_cur, h_cur, a_nxt = 0.f, h_nxt = 0.f;
  {
#pragma unroll
    for (int p = 0; p < 2; ++p) {
      int chunk = wave * 2 + p;
      GLDS16((const char*)cwb + ((size_t)(chunk * 8 + srow)) * 2048 +
                 swslot * 16,
             lds + 8192 + chunk * 1024);
    }
    a_cur = A_log[sh];
    h_cur = cbBase[sh];
#pragma unroll
    for (int j = 0; j < 16; ++j) va[j] = srcBase[(size_t)j * HID + sh];
  }

#pragma unroll
  for (int kt = 0; kt < 16; ++kt) {
    char* buf = lds + (kt % 3) * 16384;
    {
      float a = fast_exp2(a_cur * LOG2E);
      float hst = h_cur;
#pragma unroll
      for (int j = 0; j < 16; ++j) {
        hst = fmaf(a, hst, bf2f(va[j]));
        float e = fast_exp2(hst * (2.0f * LOG2E));
        float tn = fmaf(-2.0f, fast_rcp(e + 1.0f), 1.0f);
        int row = tq * 16 + j;
        *reinterpret_cast<unsigned short*>(
            buf + row * 128 + ((sh * 2) ^ ((row & 7) << 4))) = f2bf(tn);
      }
    }
    if (kt < 15) {
      char* nbuf = lds + ((kt + 1) % 3) * 16384;
#pragma unroll
      for (int p = 0; p < 2; ++p) {
        int chunk = wave * 2 + p;
        GLDS16((const char*)cwb + ((size_t)(chunk * 8 + srow)) * 2048 +
                   (kt + 1) * 128 + swslot * 16,
               nbuf + 8192 + chunk * 1024);
      }
      const int hg2 = (kt + 1) * 64 + sh;
      a_nxt = A_log[hg2];
      h_nxt = cbBase[hg2];
#pragma unroll
      for (int j = 0; j < 16; ++j) va[j] = srcBase[(size_t)j * HID + hg2];
    }
    __builtin_amdgcn_sched_barrier(0);
    asm volatile("s_waitcnt vmcnt(20)" ::: "memory");
    asm volatile("s_waitcnt lgkmcnt(0)" ::: "memory");
    __builtin_amdgcn_s_barrier();
    __builtin_amdgcn_sched_barrier(0);
    bf16x8 af[2], bfv[4][2];
#pragma unroll
    for (int kk = 0; kk < 2; ++kk) {
      int slotsw = ((kk * 4 + g) ^ (l15 & 7)) * 16;
      af[kk] = *reinterpret_cast<const bf16x8*>(buf + (wm + l15) * 128 + slotsw);
#pragma unroll
      for (int f = 0; f < 4; ++f)
        bfv[f][kk] = *reinterpret_cast<const bf16x8*>(
            buf + 8192 + (f * 16 + l15) * 128 + slotsw);
    }
#pragma unroll
    for (int kk = 0; kk < 2; ++kk)
#pragma unroll
      for (int j = 0; j < 4; ++j)
        acc[j] = __builtin_amdgcn_mfma_f32_16x16x32_bf16(
            af[kk], bfv[j][kk], acc[j], 0, 0, 0);
    a_cur = a_nxt;
    h_cur = h_nxt;
  }
  float istd[4], cb[4];
#pragma unroll
  for (int j = 0; j < 4; ++j) {
    int n = j * 16 + l15;
    istd[j] = __expf(-log_std[n]);
    cb[j] = Cb[n];
  }
  float sls = 0.f;
  for (int n = 0; n < ADIM; ++n) sls += log_std[n];
  const float cterm = -32.0f * 1.8378770664093453f - sls;
  const int rb = wm + g * 4;
#pragma unroll
  for (int r = 0; r < 4; ++r) {
    int rl = rb + r;
    int mo = (t0 + rl) * 32 + bb;
    float ss = 0.f;
#pragma unroll
    for (int j = 0; j < 4; ++j) {
      int n = j * 16 + l15;
      float mu = acc[j][r] + cb[j];
      float d = (actions[(size_t)mo * ADIM + n] - mu) * istd[j];
      ss = fmaf(d, d, ss);
    }
    ss += __shfl_xor(ss, 1);
    ss += __shfl_xor(ss, 2);
    ss += __shfl_xor(ss, 4);
    ss += __shfl_xor(ss, 8);
    if (l15 == 0) out[mo] = cterm - 0.5f * ss;
  }
}

extern "C" void kernel_launch(void* const* d_in, const int* in_sizes, int n_in,
                              void* d_out, int out_size, void* d_ws, size_t ws_size,
                              hipStream_t stream) {
  const float* states  = (const float*)d_in[0];
  const float* actions = (const float*)d_in[1];
  const float* A_log   = (const float*)d_in[2];
  const float* B_w     = (const float*)d_in[3];
  const float* B_b     = (const float*)d_in[4];
  const float* C_w     = (const float*)d_in[5];
  const float* C_b     = (const float*)d_in[6];
  const float* log_std = (const float*)d_in[7];
  float* out = (float*)d_out;
  char* ws = (char*)d_ws;

  unsigned short* bbuf = (unsigned short*)ws;
  unsigned short* stb = (unsigned short*)(ws + WS_STB);

  if (ws_size >= WS_NEED_F) {
    // tier-1: fused partials in gemm1p epilogue (m2-order), in-place carry
    float* SC = (float*)(ws + WS_SCB);
    unsigned short* bwb = (unsigned short*)(ws + WS_BWB_F);
    unsigned short* cwb = (unsigned short*)(ws + WS_CWB_F);
    k_cvt<<<8352, 256, 0, stream>>>(states, B_w, C_w, stb, bwb, cwb, 1);
    k_gemm1p_f<<<4096, 256, 0, stream>>>(stb, bwb, B_b, A_log, bbuf, SC);
    k_scan_carry_ip<<<128, 256, 0, stream>>>(SC, A_log);
    k_gemm2f<<<1024, 256, 0, stream>>>(bbuf, actions, cwb, C_b, log_std, A_log,
                                       SC, out);
  } else {
    // tier-2: round-7 proven path
    float* Sbuf = (float*)(ws + WS_SBUF2);
    float* Cbuf = (float*)(ws + WS_CBUF2);
    unsigned short* bwb = (unsigned short*)(ws + WS_BWB2);
    unsigned short* cwb = (unsigned short*)(ws + WS_CWB2);
    k_cvt<<<8352, 256, 0, stream>>>(states, B_w, C_w, stb, bwb, cwb, 0);
    k_gemm1p_7<<<4096, 256, 0, stream>>>(stb, bwb, B_b, bbuf);
    k_scan_partial<<<2048, 256, 0, stream>>>(bbuf, A_log, Sbuf);
    k_scan_carry<<<128, 256, 0, stream>>>(Sbuf, A_log, Cbuf);
    k_gemm2f<<<1024, 256, 0, stream>>>(bbuf, actions, cwb, C_b, log_std, A_log,
                                       Cbuf, out);
  }
}

// Round 13
// 116.192 us; speedup vs baseline: 2.7131x; 1.0604x over previous
//
#include <hip/hip_runtime.h>
#include <hip/hip_bf16.h>

typedef __attribute__((ext_vector_type(4))) float f32x4;
typedef __attribute__((ext_vector_type(8))) short bf16x8;

#define SDIM 256
#define HID 1024
#define ADIM 64
#define CHUNK 16
#define NCHUNK 128
#define NCH 32768  // BATCH * HID

// tier-1 (fp8 bbuf): bbuf8 [0,64M); stb [64M,96M); SC [96M,112M); bwb; cwb
#define WS8_STB  67108864ull
#define WS8_SCB  100663296ull
#define WS8_BWB  117440512ull
#define WS8_CWB  117964800ull
#define WS8_NEED 118095872ull
// tier-2 (round-7 proven, bf16 bbuf at 0, stb at 128M)
#define WS_STB2  134217728ull
#define WS_SBUF2 134217728ull
#define WS_CBUF2 150994944ull
#define WS_BWB2  167772160ull
#define WS_CWB2  168296448ull
#define WS_NEED2 168427520ull

__device__ __forceinline__ unsigned short f2bf(float f) {
  unsigned int u = __float_as_uint(f);
  u += 0x7FFF + ((u >> 16) & 1);  // RNE
  return (unsigned short)(u >> 16);
}
__device__ __forceinline__ float bf2f(unsigned short h) {
  return __uint_as_float(((unsigned int)h) << 16);
}
// pure (non-volatile): CSE-able, freely schedulable
__device__ __forceinline__ float fast_exp2(float x) {
  float r;
  asm("v_exp_f32 %0, %1" : "=v"(r) : "v"(x));
  return r;
}
__device__ __forceinline__ float fast_rcp(float x) {
  float r;
  asm("v_rcp_f32 %0, %1" : "=v"(r) : "v"(x));
  return r;
}
#define LOG2E 1.4426950408889634f

#define GLDS16(gp, lp)                                                        \
  __builtin_amdgcn_global_load_lds(                                           \
      (const __attribute__((address_space(1))) unsigned int*)(gp),            \
      (__attribute__((address_space(3))) unsigned int*)(lp), 16, 0, 0)

// ---------------- pre-convert fp32 -> bf16 (states, B_w, C_w) --------------
// perm=1: write states rows in m2-order (batch-major: m2=(m&31)*2048+(m>>5))
#define CVT_SN 16777216
#define CVT_BN 262144
#define CVT_CN 65536
__global__ __launch_bounds__(256) void k_cvt(
    const float* __restrict__ s, const float* __restrict__ bw,
    const float* __restrict__ cw, unsigned short* __restrict__ sb,
    unsigned short* __restrict__ bwb, unsigned short* __restrict__ cwb,
    int perm) {
  long long f = ((long long)blockIdx.x * 256 + threadIdx.x) * 8;
  const float* src;
  unsigned short* dst;
  long long idx, didx;
  if (f < CVT_SN) {
    src = s; dst = sb; idx = f;
    if (perm) {
      long long m = f >> 8, col = f & 255;
      didx = ((m & 31) * 2048 + (m >> 5)) * 256 + col;
    } else didx = f;
  } else if (f < CVT_SN + CVT_BN) {
    src = bw; dst = bwb; idx = f - CVT_SN; didx = idx;
  } else {
    src = cw; dst = cwb; idx = f - CVT_SN - CVT_BN; didx = idx;
  }
  float4 a = *reinterpret_cast<const float4*>(src + idx);
  float4 b = *reinterpret_cast<const float4*>(src + idx + 4);
  ushort4 lo, hi;
  lo.x = f2bf(a.x); lo.y = f2bf(a.y); lo.z = f2bf(a.z); lo.w = f2bf(a.w);
  hi.x = f2bf(b.x); hi.y = f2bf(b.y); hi.z = f2bf(b.z); hi.w = f2bf(b.w);
  *reinterpret_cast<ushort4*>(dst + didx) = lo;
  *reinterpret_cast<ushort4*>(dst + didx + 4) = hi;
}

// -------------------- shared GEMM1 compute (r4/r7 proven) ------------------
__device__ __forceinline__ void g1_compute(
    const char* bA, const char* bB, f32x4 (&acc)[4][4],
    int wm, int wn, int l15, int g) {
  bf16x8 af[4][2], bfv[4][2];
#pragma unroll
  for (int kk = 0; kk < 2; ++kk) {
    int slotsw = ((kk * 4 + g) ^ (l15 & 7)) * 16;
#pragma unroll
    for (int f = 0; f < 4; ++f) {
      af[f][kk] = *reinterpret_cast<const bf16x8*>(bA + (wm + f * 16 + l15) * 128 + slotsw);
      bfv[f][kk] = *reinterpret_cast<const bf16x8*>(bB + (wn + f * 16 + l15) * 128 + slotsw);
    }
  }
#pragma unroll
  for (int kk = 0; kk < 2; ++kk)
#pragma unroll
    for (int i = 0; i < 4; ++i)
#pragma unroll
      for (int j = 0; j < 4; ++j)
        acc[i][j] = __builtin_amdgcn_mfma_f32_16x16x32_bf16(
            bfv[j][kk], af[i][kk], acc[i][j], 0, 0, 0);
}

#define STAGE1(tile, buf)                                                     \
  {                                                                           \
    const int k0b_ = (tile) * 128;                                            \
    char* dA_ = lds + (buf) * 32768;                                          \
    char* dB_ = lds + 16384 + (buf) * 32768;                                  \
    _Pragma("unroll")                                                         \
    for (int p = 0; p < 4; ++p) {                                             \
      int chunk = wave * 4 + p;                                               \
      GLDS16((const char*)sb + ((size_t)(m0 + chunk * 8 + srow) * SDIM) * 2 + \
                 k0b_ + swslot * 16,                                          \
             dA_ + chunk * 1024);                                             \
      GLDS16((const char*)bwb + ((size_t)(n0 + chunk * 8 + srow) * SDIM) * 2 +\
                 k0b_ + swslot * 16,                                          \
             dB_ + chunk * 1024);                                             \
    }                                                                         \
  }

#define G1_PIPELINE()                                                         \
  STAGE1(0, 0);                                                               \
  for (int t = 0; t < 3; ++t) {                                               \
    const int cur = t & 1;                                                    \
    STAGE1(t + 1, cur ^ 1);                                                   \
    asm volatile("s_waitcnt vmcnt(8)" ::: "memory");                          \
    __builtin_amdgcn_s_barrier();                                             \
    __builtin_amdgcn_sched_barrier(0);                                        \
    g1_compute(lds + cur * 32768, lds + 16384 + cur * 32768, acc, wm, wn,     \
               l15, g);                                                       \
    __builtin_amdgcn_s_barrier();                                             \
    __builtin_amdgcn_sched_barrier(0);                                        \
  }                                                                           \
  asm volatile("s_waitcnt vmcnt(0)" ::: "memory");                            \
  __builtin_amdgcn_s_barrier();                                               \
  __builtin_amdgcn_sched_barrier(0);                                          \
  g1_compute(lds + 32768, lds + 16384 + 32768, acc, wm, wn, l15, g);          \
  __builtin_amdgcn_s_barrier();                                               \
  __builtin_amdgcn_sched_barrier(0);

// ---- K1 tier-1: b = states@B_w^T+B_b -> bbuf8[b][t][h] (fp8 e4m3) ----
// r7 staging/MFMA; epilogue emits fp8 b + per-16t chunk partials (Horner,
// computed from the bf16 wb tile BEFORE fp8 pack -> carries stay accurate).
__global__ __launch_bounds__(256) void k_gemm1p_f(
    const unsigned short* __restrict__ sb, const unsigned short* __restrict__ bwb,
    const float* __restrict__ Bb, const float* __restrict__ A_log,
    unsigned char* __restrict__ bout8, float* __restrict__ Sb) {
  __shared__ char lds[65536];
  const int tid = threadIdx.x;
  const int wave = tid >> 6, lane = tid & 63;
  const int l15 = lane & 15, g = lane >> 4;
  const int bx = blockIdx.x;
  const int swzb = (bx & 7) * 512 + (bx >> 3);  // bijective XCD swizzle
  const int mt = swzb >> 3, nt = swzb & 7;
  const int m0 = mt * 128, n0 = nt * 128;  // m0 = m2-row base (batch-major)
  const int bb2 = mt >> 4;                 // batch of this tile
  const int c0t = (mt & 15) * 8;           // global t-chunk base
  const int wm = (wave >> 1) * 64, wn = (wave & 1) * 64;
  const int srow = lane >> 3;
  const int swslot = (lane & 7) ^ srow;

  f32x4 acc[4][4];
#pragma unroll
  for (int i = 0; i < 4; i++)
#pragma unroll
    for (int j = 0; j < 4; j++) acc[i][j] = (f32x4){0.f, 0.f, 0.f, 0.f};

  G1_PIPELINE();

  // epilogue part 1: bias + pack, per-wave LDS transpose (r7 verbatim)
  char* wb = lds + wave * 9216;
#pragma unroll
  for (int j = 0; j < 4; ++j) {
    float4 bb = *reinterpret_cast<const float4*>(Bb + n0 + wn + j * 16 + g * 4);
#pragma unroll
    for (int i = 0; i < 4; ++i) {
      ushort4 w;
      w.x = f2bf(acc[i][j][0] + bb.x);
      w.y = f2bf(acc[i][j][1] + bb.y);
      w.z = f2bf(acc[i][j][2] + bb.z);
      w.w = f2bf(acc[i][j][3] + bb.w);
      *reinterpret_cast<ushort4*>(wb + (i * 16 + l15) * 144 + j * 32 + g * 8) = w;
    }
  }
  const int h8 = lane & 7;
  const int lr = lane >> 3;
  // epilogue part 2a: fp8 pack + coalesced global store (8B/lane)
#pragma unroll
  for (int tt = 0; tt < 8; ++tt) {
    int ml = lr + tt * 8;
    int4 v = *reinterpret_cast<const int4*>(wb + ml * 144 + h8 * 16);
    unsigned int u[4] = {(unsigned)v.x, (unsigned)v.y, (unsigned)v.z,
                         (unsigned)v.w};
    float f[8];
#pragma unroll
    for (int e = 0; e < 8; ++e) {
      unsigned int bits = (e & 1) ? (u[e >> 1] & 0xFFFF0000u) : (u[e >> 1] << 16);
      f[e] = __uint_as_float(bits);
    }
    int d0 = __builtin_amdgcn_cvt_pk_fp8_f32(f[0], f[1], 0, 0);
    d0 = __builtin_amdgcn_cvt_pk_fp8_f32(f[2], f[3], d0, 1);
    int d1 = __builtin_amdgcn_cvt_pk_fp8_f32(f[4], f[5], 0, 0);
    d1 = __builtin_amdgcn_cvt_pk_fp8_f32(f[6], f[7], d1, 1);
    int2 o = {d0, d1};
    *reinterpret_cast<int2*>(bout8 + (size_t)(m0 + wm + ml) * HID + n0 + wn +
                             h8 * 8) = o;
  }
  // epilogue part 2b: chunk partials via Horner (bf16-accurate; r12 proven)
  {
    const int c = lr >> 1, half = lr & 1;
    float a1v[8], a8v[8];
    {
      float4 a0 = *reinterpret_cast<const float4*>(A_log + n0 + wn + h8 * 8);
      float4 a1_ = *reinterpret_cast<const float4*>(A_log + n0 + wn + h8 * 8 + 4);
      float al8[8] = {a0.x, a0.y, a0.z, a0.w, a1_.x, a1_.y, a1_.z, a1_.w};
#pragma unroll
      for (int e = 0; e < 8; ++e) {
        a1v[e] = fast_exp2(al8[e] * LOG2E);
        a8v[e] = fast_exp2(al8[e] * (8.0f * LOG2E));
      }
    }
    float s8[8] = {0.f, 0.f, 0.f, 0.f, 0.f, 0.f, 0.f, 0.f};
#pragma unroll
    for (int j = 0; j < 8; ++j) {
      int ml = c * 16 + half * 8 + j;
      int4 v = *reinterpret_cast<const int4*>(wb + ml * 144 + h8 * 16);
      unsigned int u[4] = {(unsigned)v.x, (unsigned)v.y, (unsigned)v.z,
                           (unsigned)v.w};
#pragma unroll
      for (int e = 0; e < 8; ++e) {
        unsigned int bits = (e & 1) ? (u[e >> 1] & 0xFFFF0000u) : (u[e >> 1] << 16);
        s8[e] = fmaf(a1v[e], s8[e], __uint_as_float(bits));
      }
    }
    const float hsel = half ? 1.0f : 0.0f;
#pragma unroll
    for (int e = 0; e < 8; ++e) {
      float scale = hsel + (1.0f - hsel) * a8v[e];  // half?1:a^8, branchless
      s8[e] *= scale;
      s8[e] += __shfl_xor(s8[e], 8);
    }
    if (half == 0) {
      int cg = c0t + (wm >> 4) + c;
      float4 o0 = {s8[0], s8[1], s8[2], s8[3]};
      float4 o1 = {s8[4], s8[5], s8[6], s8[7]};
      float* sp = Sb + (size_t)cg * NCH + bb2 * 1024 + n0 + wn + h8 * 8;
      *reinterpret_cast<float4*>(sp) = o0;
      *reinterpret_cast<float4*>(sp + 4) = o1;
    }
  }
}

// ---- K1 tier-2: r7 verbatim (m-order tiles, permuted bf16 store) ----
__global__ __launch_bounds__(256) void k_gemm1p_7(
    const unsigned short* __restrict__ sb, const unsigned short* __restrict__ bwb,
    const float* __restrict__ Bb, unsigned short* __restrict__ bout) {
  __shared__ char lds[65536];
  const int tid = threadIdx.x;
  const int wave = tid >> 6, lane = tid & 63;
  const int l15 = lane & 15, g = lane >> 4;
  const int bx = blockIdx.x;
  const int swzb = (bx & 7) * 512 + (bx >> 3);
  const int m0 = (swzb >> 3) * 128, n0 = (swzb & 7) * 128;
  const int wm = (wave >> 1) * 64, wn = (wave & 1) * 64;
  const int srow = lane >> 3;
  const int swslot = (lane & 7) ^ srow;

  f32x4 acc[4][4];
#pragma unroll
  for (int i = 0; i < 4; i++)
#pragma unroll
    for (int j = 0; j < 4; j++) acc[i][j] = (f32x4){0.f, 0.f, 0.f, 0.f};

  G1_PIPELINE();

  char* wb = lds + wave * 9216;
#pragma unroll
  for (int j = 0; j < 4; ++j) {
    float4 bb = *reinterpret_cast<const float4*>(Bb + n0 + wn + j * 16 + g * 4);
#pragma unroll
    for (int i = 0; i < 4; ++i) {
      ushort4 w;
      w.x = f2bf(acc[i][j][0] + bb.x);
      w.y = f2bf(acc[i][j][1] + bb.y);
      w.z = f2bf(acc[i][j][2] + bb.z);
      w.w = f2bf(acc[i][j][3] + bb.w);
      *reinterpret_cast<ushort4*>(wb + (i * 16 + l15) * 144 + j * 32 + g * 8) = w;
    }
  }
#pragma unroll
  for (int tt = 0; tt < 8; ++tt) {
    int ml = (lane >> 3) + tt * 8;
    int4 v = *reinterpret_cast<const int4*>(wb + ml * 144 + (lane & 7) * 16);
    int m = m0 + wm + ml;  // m = t*32 + batch
    size_t dst = ((size_t)(m & 31) * 2048 + (size_t)(m >> 5)) * HID +
                 n0 + wn + (lane & 7) * 8;
    *reinterpret_cast<int4*>(bout + dst) = v;
  }
}

// ------------- K2a (tier-2 only): per-chunk partial scan sums -----------
__global__ __launch_bounds__(256) void k_scan_partial(
    const unsigned short* __restrict__ b2, const float* __restrict__ A_log,
    float* __restrict__ Sbuf) {
  int gid = blockIdx.x * 256 + threadIdx.x;
  int ch = (gid & 4095) * 8;
  int c = gid >> 12;
  int bb = ch >> 10;
  int hh = ch & 1023;
  float4 al0 = *reinterpret_cast<const float4*>(A_log + hh);
  float4 al1 = *reinterpret_cast<const float4*>(A_log + hh + 4);
  float a[8] = {__expf(al0.x), __expf(al0.y), __expf(al0.z), __expf(al0.w),
                __expf(al1.x), __expf(al1.y), __expf(al1.z), __expf(al1.w)};
  const unsigned short* p = b2 + (size_t)bb * 2097152 + (size_t)c * CHUNK * HID + hh;
  float s[8] = {0.f, 0.f, 0.f, 0.f, 0.f, 0.f, 0.f, 0.f};
#pragma unroll 4
  for (int j = 0; j < CHUNK; ++j) {
    int4 v = *reinterpret_cast<const int4*>(p + (size_t)j * HID);
    unsigned int u[4] = {(unsigned)v.x, (unsigned)v.y, (unsigned)v.z, (unsigned)v.w};
#pragma unroll
    for (int e = 0; e < 4; ++e) {
      s[2 * e]     = fmaf(a[2 * e],     s[2 * e],     __uint_as_float(u[e] << 16));
      s[2 * e + 1] = fmaf(a[2 * e + 1], s[2 * e + 1], __uint_as_float(u[e] & 0xFFFF0000u));
    }
  }
  float4 o0 = {s[0], s[1], s[2], s[3]}, o1 = {s[4], s[5], s[6], s[7]};
  *reinterpret_cast<float4*>(Sbuf + (size_t)c * NCH + ch) = o0;
  *reinterpret_cast<float4*>(Sbuf + (size_t)c * NCH + ch + 4) = o1;
}

// ------------- K2b: carry scan (separate-buffer, tier-2) ----------------
__global__ __launch_bounds__(256) void k_scan_carry(
    const float* __restrict__ Sbuf, const float* __restrict__ A_log,
    float* __restrict__ Cbuf) {
  int ch = blockIdx.x * 256 + threadIdx.x;
  float aL = __expf(A_log[ch & (HID - 1)] * (float)CHUNK);
  float h = 0.f;
  for (int c = 0; c < NCHUNK; ++c) {
    Cbuf[(size_t)c * NCH + ch] = h;
    h = fmaf(aL, h, Sbuf[(size_t)c * NCH + ch]);
  }
}

// ------------- K2b': in-place carry (tier-1): S[c] -> C[c] ----------------
__global__ __launch_bounds__(256) void k_scan_carry_ip(
    float* __restrict__ SC, const float* __restrict__ A_log) {
  int ch = blockIdx.x * 256 + threadIdx.x;
  float aL = __expf(A_log[ch & (HID - 1)] * (float)CHUNK);
  float h = 0.f;
  for (int c = 0; c < NCHUNK; ++c) {
    float tmp = SC[(size_t)c * NCH + ch];
    SC[(size_t)c * NCH + ch] = h;
    h = fmaf(aL, h, tmp);
  }
}

// ---- K3 (templated dtype): scan+tanh + mus GEMM + log-prob ----
template <int FP8>
__global__ __launch_bounds__(256) void k_gemm2f_t(
    const void* __restrict__ b2v, const float* __restrict__ actions,
    const unsigned short* __restrict__ cwb, const float* __restrict__ Cb,
    const float* __restrict__ log_std, const float* __restrict__ A_log,
    const float* __restrict__ Cbuf, float* __restrict__ out) {
  __shared__ char lds[49152];  // 3 bufs x {A(8K)|B(8K)}
  const int tid = threadIdx.x;
  const int wave = tid >> 6, lane = tid & 63;
  const int l15 = lane & 15, g = lane >> 4;
  const int bq = blockIdx.x;
  const int bb = bq >> 5;
  const int t0 = (bq & 31) * 64;
  const int c0 = t0 >> 4;
  const int wm = wave * 16;
  const int srow = lane >> 3;
  const int swslot = (lane & 7) ^ srow;
  const int sh = tid & 63;
  const int tq = tid >> 6;

  const size_t elemBase = (size_t)bb * 2097152 + (size_t)(t0 + tq * 16) * HID;
  const unsigned char* srcB8 = (const unsigned char*)b2v + elemBase;
  const unsigned short* srcB16 = (const unsigned short*)b2v + elemBase;
  const float* cbBase = Cbuf + (size_t)(c0 + tq) * NCH + bb * 1024;

  f32x4 acc[4];
#pragma unroll
  for (int j = 0; j < 4; j++) acc[j] = (f32x4){0.f, 0.f, 0.f, 0.f};

  unsigned short va[16];
  float a_cur, h_cur, a_nxt = 0.f, h_nxt = 0.f;
  {
#pragma unroll
    for (int p = 0; p < 2; ++p) {
      int chunk = wave * 2 + p;
      GLDS16((const char*)cwb + ((size_t)(chunk * 8 + srow)) * 2048 +
                 swslot * 16,
             lds + 8192 + chunk * 1024);
    }
    a_cur = A_log[sh];
    h_cur = cbBase[sh];
#pragma unroll
    for (int j = 0; j < 16; ++j)
      va[j] = FP8 ? (unsigned short)srcB8[(size_t)j * HID + sh]
                  : srcB16[(size_t)j * HID + sh];
  }

#pragma unroll
  for (int kt = 0; kt < 16; ++kt) {
    char* buf = lds + (kt % 3) * 16384;
    {
      float a = fast_exp2(a_cur * LOG2E);
      float hst = h_cur;
#pragma unroll
      for (int j = 0; j < 16; ++j) {
        float bval = FP8 ? __builtin_amdgcn_cvt_f32_fp8((int)va[j], 0)
                         : bf2f(va[j]);
        hst = fmaf(a, hst, bval);
        float e = fast_exp2(hst * (2.0f * LOG2E));
        float tn = fmaf(-2.0f, fast_rcp(e + 1.0f), 1.0f);
        int row = tq * 16 + j;
        *reinterpret_cast<unsigned short*>(
            buf + row * 128 + ((sh * 2) ^ ((row & 7) << 4))) = f2bf(tn);
      }
    }
    if (kt < 15) {
      char* nbuf = lds + ((kt + 1) % 3) * 16384;
#pragma unroll
      for (int p = 0; p < 2; ++p) {
        int chunk = wave * 2 + p;
        GLDS16((const char*)cwb + ((size_t)(chunk * 8 + srow)) * 2048 +
                   (kt + 1) * 128 + swslot * 16,
               nbuf + 8192 + chunk * 1024);
      }
      const int hg2 = (kt + 1) * 64 + sh;
      a_nxt = A_log[hg2];
      h_nxt = cbBase[hg2];
#pragma unroll
      for (int j = 0; j < 16; ++j)
        va[j] = FP8 ? (unsigned short)srcB8[(size_t)j * HID + hg2]
                    : srcB16[(size_t)j * HID + hg2];
    }
    __builtin_amdgcn_sched_barrier(0);
    asm volatile("s_waitcnt vmcnt(20)" ::: "memory");
    asm volatile("s_waitcnt lgkmcnt(0)" ::: "memory");
    __builtin_amdgcn_s_barrier();
    __builtin_amdgcn_sched_barrier(0);
    bf16x8 af[2], bfv[4][2];
#pragma unroll
    for (int kk = 0; kk < 2; ++kk) {
      int slotsw = ((kk * 4 + g) ^ (l15 & 7)) * 16;
      af[kk] = *reinterpret_cast<const bf16x8*>(buf + (wm + l15) * 128 + slotsw);
#pragma unroll
      for (int f = 0; f < 4; ++f)
        bfv[f][kk] = *reinterpret_cast<const bf16x8*>(
            buf + 8192 + (f * 16 + l15) * 128 + slotsw);
    }
#pragma unroll
    for (int kk = 0; kk < 2; ++kk)
#pragma unroll
      for (int j = 0; j < 4; ++j)
        acc[j] = __builtin_amdgcn_mfma_f32_16x16x32_bf16(
            af[kk], bfv[j][kk], acc[j], 0, 0, 0);
    a_cur = a_nxt;
    h_cur = h_nxt;
  }
  float istd[4], cb[4];
#pragma unroll
  for (int j = 0; j < 4; ++j) {
    int n = j * 16 + l15;
    istd[j] = __expf(-log_std[n]);
    cb[j] = Cb[n];
  }
  float sls = 0.f;
  for (int n = 0; n < ADIM; ++n) sls += log_std[n];
  const float cterm = -32.0f * 1.8378770664093453f - sls;
  const int rb = wm + g * 4;
#pragma unroll
  for (int r = 0; r < 4; ++r) {
    int rl = rb + r;
    int mo = (t0 + rl) * 32 + bb;
    float ss = 0.f;
#pragma unroll
    for (int j = 0; j < 4; ++j) {
      int n = j * 16 + l15;
      float mu = acc[j][r] + cb[j];
      float d = (actions[(size_t)mo * ADIM + n] - mu) * istd[j];
      ss = fmaf(d, d, ss);
    }
    ss += __shfl_xor(ss, 1);
    ss += __shfl_xor(ss, 2);
    ss += __shfl_xor(ss, 4);
    ss += __shfl_xor(ss, 8);
    if (l15 == 0) out[mo] = cterm - 0.5f * ss;
  }
}

extern "C" void kernel_launch(void* const* d_in, const int* in_sizes, int n_in,
                              void* d_out, int out_size, void* d_ws, size_t ws_size,
                              hipStream_t stream) {
  const float* states  = (const float*)d_in[0];
  const float* actions = (const float*)d_in[1];
  const float* A_log   = (const float*)d_in[2];
  const float* B_w     = (const float*)d_in[3];
  const float* B_b     = (const float*)d_in[4];
  const float* C_w     = (const float*)d_in[5];
  const float* C_b     = (const float*)d_in[6];
  const float* log_std = (const float*)d_in[7];
  float* out = (float*)d_out;
  char* ws = (char*)d_ws;

  if (ws_size >= WS8_NEED) {
    // tier-1: fp8 bbuf, fused partials in gemm1p epilogue, in-place carry
    unsigned char* bbuf8 = (unsigned char*)ws;
    unsigned short* stb = (unsigned short*)(ws + WS8_STB);
    float* SC = (float*)(ws + WS8_SCB);
    unsigned short* bwb = (unsigned short*)(ws + WS8_BWB);
    unsigned short* cwb = (unsigned short*)(ws + WS8_CWB);
    k_cvt<<<8352, 256, 0, stream>>>(states, B_w, C_w, stb, bwb, cwb, 1);
    k_gemm1p_f<<<4096, 256, 0, stream>>>(stb, bwb, B_b, A_log, bbuf8, SC);
    k_scan_carry_ip<<<128, 256, 0, stream>>>(SC, A_log);
    k_gemm2f_t<1><<<1024, 256, 0, stream>>>(bbuf8, actions, cwb, C_b, log_std,
                                            A_log, SC, out);
  } else {
    // tier-2: round-7 proven path (bf16 bbuf)
    unsigned short* bbuf = (unsigned short*)ws;
    unsigned short* stb = (unsigned short*)(ws + WS_STB2);
    float* Sbuf = (float*)(ws + WS_SBUF2);
    float* Cbuf = (float*)(ws + WS_CBUF2);
    unsigned short* bwb = (unsigned short*)(ws + WS_BWB2);
    unsigned short* cwb = (unsigned short*)(ws + WS_CWB2);
    k_cvt<<<8352, 256, 0, stream>>>(states, B_w, C_w, stb, bwb, cwb, 0);
    k_gemm1p_7<<<4096, 256, 0, stream>>>(stb, bwb, B_b, bbuf);
    k_scan_partial<<<2048, 256, 0, stream>>>(bbuf, A_log, Sbuf);
    k_scan_carry<<<128, 256, 0, stream>>>(Sbuf, A_log, Cbuf);
    k_gemm2f_t<0><<<1024, 256, 0, stream>>>(bbuf, actions, cwb, C_b, log_std,
                                            A_log, Cbuf, out);
  }
}